// Round 2
// baseline (1456.069 us; speedup 1.0000x reference)
//
#include <hip/hip_runtime.h>

#define NNODES 200000
#define NEDGES 6400000
#define FIN 7
#define FH1 32
#define FH2 16
#define NC 2

// bucketing: sort key = (dest bucket, source chunk)
#define WB 128                       // nodes per dest bucket
#define WB_SHIFT 7
#define NBUCK ((NNODES + WB - 1) / WB)   // 1563
#define CSHIFT 15                    // source chunk = 32768 nodes -> y slice 2 MB (fits per-XCD L2)
#define NCHUNK ((NNODES + (1 << CSHIFT) - 1) >> CSHIFT)  // 7
#define NKEY (NBUCK * NCHUNK)        // 10941
#define PSHIFT 18
#define SRCMASK ((1u << PSHIFT) - 1)

#define NBLK_P1 128
#define CHUNK_P1 ((NEDGES + NBLK_P1 - 1) / NBLK_P1)  // 50000
#define NBLK_P2 256
#define CHUNK_P2 ((NEDGES + NBLK_P2 - 1) / NBLK_P2)  // 25000

#define SCAN_T 1024
#define SCAN_IT ((NKEY + SCAN_T - 1) / SCAN_T)       // 11

// ---------------- zero the global histogram ----------------

__global__ __launch_bounds__(256) void zero_counts(int* __restrict__ counts) {
    int i = blockIdx.x * 256 + threadIdx.x;
    if (i < NKEY) counts[i] = 0;
}

// ---------------- P1: per-block LDS histogram -> global counts ----------------

__global__ __launch_bounds__(256) void p1_count(const int* __restrict__ ei,
                                                int* __restrict__ counts) {
    __shared__ int h[NKEY];   // 43.7 KB
    for (int i = threadIdx.x; i < NKEY; i += 256) h[i] = 0;
    __syncthreads();
    int base = blockIdx.x * CHUNK_P1;
    int end = base + CHUNK_P1;
    if (end > NEDGES) end = NEDGES;
    for (int e = base + threadIdx.x; e < end; e += 256) {
        int s = ei[e];
        int d = ei[NEDGES + e];
        atomicAdd(&h[(d >> WB_SHIFT) * NCHUNK + (s >> CSHIFT)], 1);
    }
    __syncthreads();
    for (int i = threadIdx.x; i < NKEY; i += 256) {
        int v = h[i];
        if (v) atomicAdd(&counts[i], v);
    }
}

// ---------------- single-block exclusive scan of counts[NKEY] ----------------

__global__ __launch_bounds__(SCAN_T) void scan_small(const int* __restrict__ counts,
                                                     int* __restrict__ offs,
                                                     int* __restrict__ cur) {
    __shared__ int sm[SCAN_T];
    int t = threadIdx.x;
    int base = t * SCAN_IT;
    int local[SCAN_IT];
    int s = 0;
#pragma unroll
    for (int k = 0; k < SCAN_IT; ++k) {
        int idx = base + k;
        int v = (idx < NKEY) ? counts[idx] : 0;
        local[k] = v;
        s += v;
    }
    sm[t] = s;
    __syncthreads();
    for (int off = 1; off < SCAN_T; off <<= 1) {
        int v = (t >= off) ? sm[t - off] : 0;
        __syncthreads();
        sm[t] += v;
        __syncthreads();
    }
    int prefix = sm[t] - s;  // exclusive
#pragma unroll
    for (int k = 0; k < SCAN_IT; ++k) {
        int idx = base + k;
        if (idx < NKEY) {
            offs[idx] = prefix;
            cur[idx]  = prefix;
            prefix += local[k];
        }
    }
}

// ---------------- P2: scatter packed records via global slot allocation ----------------

__global__ __launch_bounds__(256) void p2_scatter(const int* __restrict__ ei,
                                                  int* __restrict__ cur,
                                                  unsigned int* __restrict__ recs) {
    int base = blockIdx.x * CHUNK_P2;
    int end = base + CHUNK_P2;
    if (end > NEDGES) end = NEDGES;
    for (int e = base + threadIdx.x; e < end; e += 256) {
        int s = ei[e];
        int d = ei[NEDGES + e];
        int key = (d >> WB_SHIFT) * NCHUNK + (s >> CSHIFT);
        int slot = atomicAdd(&cur[key], 1);
        recs[slot] = (unsigned)s | ((unsigned)(d & (WB - 1)) << PSHIFT);
    }
}

// ---------------- P3: per-bucket degree -> dinv ----------------

__global__ __launch_bounds__(256) void p3_dinv(const unsigned int* __restrict__ recs,
                                               const int* __restrict__ offs,
                                               float* __restrict__ dinv) {
    __shared__ int h[WB];
    int b = blockIdx.x;
    if (threadIdx.x < WB) h[threadIdx.x] = 0;
    __syncthreads();
    int beg = offs[b * NCHUNK];
    int end = (b + 1 < NBUCK) ? offs[(b + 1) * NCHUNK] : NEDGES;
    for (int e = beg + threadIdx.x; e < end; e += 256)
        atomicAdd(&h[recs[e] >> PSHIFT], 1);
    __syncthreads();
    int node = b * WB + threadIdx.x;
    if (threadIdx.x < WB && node < NNODES)
        dinv[node] = rsqrtf((float)(1 + h[threadIdx.x]));
}

// ---------------- gx = dinv * x, padded 7 -> 8 ----------------

__global__ __launch_bounds__(256) void gx_kernel(const float* __restrict__ x,
                                                 const float* __restrict__ dinv,
                                                 float4* __restrict__ gx) {
    int i = blockIdx.x * blockDim.x + threadIdx.x;
    if (i >= NNODES) return;
    float di = dinv[i];
    const float* xr = x + (size_t)i * FIN;
    float4 v0, v1;
    v0.x = xr[0] * di; v0.y = xr[1] * di; v0.z = xr[2] * di; v0.w = xr[3] * di;
    v1.x = xr[4] * di; v1.y = xr[5] * di; v1.z = xr[6] * di; v1.w = 0.0f;
    gx[(size_t)i * 2 + 0] = v0;
    gx[(size_t)i * 2 + 1] = v1;
}

// ---------------- L1: bucket-wise aggregate(gx) -> W1 -> relu -> W2 -> scale ----------------

__global__ __launch_bounds__(256) void l1_bucket(const unsigned int* __restrict__ recs,
                                                 const int* __restrict__ offs,
                                                 const float4* __restrict__ gx,
                                                 const float* __restrict__ dinv,
                                                 const float* __restrict__ W1,
                                                 const float* __restrict__ b1,
                                                 const float* __restrict__ W2,
                                                 float4* __restrict__ y) {
    __shared__ float acc[WB][9];   // pad 8->9: break stride-8 bank pattern
    __shared__ float sW1[FIN * FH1];
    __shared__ float sb1[FH1];
    __shared__ float sW2[FH1 * FH2];
    int t = threadIdx.x;
    for (int i = t; i < FIN * FH1; i += 256) sW1[i] = W1[i];
    if (t < FH1) sb1[t] = b1[t];
    for (int i = t; i < FH1 * FH2; i += 256) sW2[i] = W2[i];
    for (int i = t; i < WB * 9; i += 256) ((float*)acc)[i] = 0.0f;
    __syncthreads();

    int b = blockIdx.x;
    int beg = offs[b * NCHUNK];
    int end = (b + 1 < NBUCK) ? offs[(b + 1) * NCHUNK] : NEDGES;

    int e = beg + t;
    for (; e + 256 < end; e += 512) {
        unsigned r0 = recs[e];
        unsigned r1 = recs[e + 256];
        int s0 = r0 & SRCMASK, d0 = r0 >> PSHIFT;
        int s1 = r1 & SRCMASK, d1 = r1 >> PSHIFT;
        float4 a0 = gx[(size_t)s0 * 2], a1 = gx[(size_t)s0 * 2 + 1];
        float4 c0 = gx[(size_t)s1 * 2], c1 = gx[(size_t)s1 * 2 + 1];
        atomicAdd(&acc[d0][0], a0.x); atomicAdd(&acc[d0][1], a0.y);
        atomicAdd(&acc[d0][2], a0.z); atomicAdd(&acc[d0][3], a0.w);
        atomicAdd(&acc[d0][4], a1.x); atomicAdd(&acc[d0][5], a1.y);
        atomicAdd(&acc[d0][6], a1.z);
        atomicAdd(&acc[d1][0], c0.x); atomicAdd(&acc[d1][1], c0.y);
        atomicAdd(&acc[d1][2], c0.z); atomicAdd(&acc[d1][3], c0.w);
        atomicAdd(&acc[d1][4], c1.x); atomicAdd(&acc[d1][5], c1.y);
        atomicAdd(&acc[d1][6], c1.z);
    }
    if (e < end) {
        unsigned r0 = recs[e];
        int s0 = r0 & SRCMASK, d0 = r0 >> PSHIFT;
        float4 a0 = gx[(size_t)s0 * 2], a1 = gx[(size_t)s0 * 2 + 1];
        atomicAdd(&acc[d0][0], a0.x); atomicAdd(&acc[d0][1], a0.y);
        atomicAdd(&acc[d0][2], a0.z); atomicAdd(&acc[d0][3], a0.w);
        atomicAdd(&acc[d0][4], a1.x); atomicAdd(&acc[d0][5], a1.y);
        atomicAdd(&acc[d0][6], a1.z);
    }
    __syncthreads();

    int node = b * WB + t;
    if (t >= WB || node >= NNODES) return;

    float di = dinv[node];
    float4 g0 = gx[(size_t)node * 2], g1 = gx[(size_t)node * 2 + 1];
    float xa[FIN];
    xa[0] = (acc[t][0] + g0.x) * di;
    xa[1] = (acc[t][1] + g0.y) * di;
    xa[2] = (acc[t][2] + g0.z) * di;
    xa[3] = (acc[t][3] + g0.w) * di;
    xa[4] = (acc[t][4] + g1.x) * di;
    xa[5] = (acc[t][5] + g1.y) * di;
    xa[6] = (acc[t][6] + g1.z) * di;

    float h1[FH1];
#pragma unroll
    for (int j = 0; j < FH1; ++j) h1[j] = sb1[j];
#pragma unroll
    for (int f = 0; f < FIN; ++f) {
        float xv = xa[f];
#pragma unroll
        for (int j = 0; j < FH1; ++j) h1[j] = fmaf(xv, sW1[f * FH1 + j], h1[j]);
    }
#pragma unroll
    for (int j = 0; j < FH1; ++j) h1[j] = fmaxf(h1[j], 0.0f);

    float yv[FH2];
#pragma unroll
    for (int j = 0; j < FH2; ++j) yv[j] = 0.0f;
#pragma unroll
    for (int k = 0; k < FH1; ++k) {
        float hv = h1[k];
#pragma unroll
        for (int j = 0; j < FH2; ++j) yv[j] = fmaf(hv, sW2[k * FH2 + j], yv[j]);
    }

    size_t yb = (size_t)node * 4;
    float4 o;
    o.x = yv[0] * di; o.y = yv[1] * di; o.z = yv[2] * di; o.w = yv[3] * di;
    y[yb + 0] = o;
    o.x = yv[4] * di; o.y = yv[5] * di; o.z = yv[6] * di; o.w = yv[7] * di;
    y[yb + 1] = o;
    o.x = yv[8] * di; o.y = yv[9] * di; o.z = yv[10] * di; o.w = yv[11] * di;
    y[yb + 2] = o;
    o.x = yv[12] * di; o.y = yv[13] * di; o.z = yv[14] * di; o.w = yv[15] * di;
    y[yb + 3] = o;
}

// ---------------- L2: bucket-wise aggregate(y) -> +b2 -> relu -> Wfc ----------------

__global__ __launch_bounds__(256) void l2_bucket(const unsigned int* __restrict__ recs,
                                                 const int* __restrict__ offs,
                                                 const float4* __restrict__ y,
                                                 const float* __restrict__ dinv,
                                                 const float* __restrict__ b2,
                                                 const float* __restrict__ Wfc,
                                                 const float* __restrict__ bfc,
                                                 float2* __restrict__ out) {
    __shared__ float acc[WB][17];  // pad 16->17: break stride-16 bank pattern
    __shared__ float sb2[FH2];
    __shared__ float sWfc[FH2 * NC];
    __shared__ float sbfc[NC];
    int t = threadIdx.x;
    if (t < FH2) sb2[t] = b2[t];
    if (t < FH2 * NC) sWfc[t] = Wfc[t];
    if (t < NC) sbfc[t] = bfc[t];
    for (int i = t; i < WB * 17; i += 256) ((float*)acc)[i] = 0.0f;
    __syncthreads();

    int b = blockIdx.x;
    int beg = offs[b * NCHUNK];
    int end = (b + 1 < NBUCK) ? offs[(b + 1) * NCHUNK] : NEDGES;

    int e = beg + t;
    for (; e + 256 < end; e += 512) {
        unsigned r0 = recs[e];
        unsigned r1 = recs[e + 256];
        int s0 = r0 & SRCMASK, d0 = r0 >> PSHIFT;
        int s1 = r1 & SRCMASK, d1 = r1 >> PSHIFT;
        size_t sa = (size_t)s0 * 4;
        size_t sc = (size_t)s1 * 4;
        float4 p0 = y[sa + 0], p1 = y[sa + 1], p2 = y[sa + 2], p3 = y[sa + 3];
        float4 q0 = y[sc + 0], q1 = y[sc + 1], q2 = y[sc + 2], q3 = y[sc + 3];
        atomicAdd(&acc[d0][0],  p0.x); atomicAdd(&acc[d0][1],  p0.y);
        atomicAdd(&acc[d0][2],  p0.z); atomicAdd(&acc[d0][3],  p0.w);
        atomicAdd(&acc[d0][4],  p1.x); atomicAdd(&acc[d0][5],  p1.y);
        atomicAdd(&acc[d0][6],  p1.z); atomicAdd(&acc[d0][7],  p1.w);
        atomicAdd(&acc[d0][8],  p2.x); atomicAdd(&acc[d0][9],  p2.y);
        atomicAdd(&acc[d0][10], p2.z); atomicAdd(&acc[d0][11], p2.w);
        atomicAdd(&acc[d0][12], p3.x); atomicAdd(&acc[d0][13], p3.y);
        atomicAdd(&acc[d0][14], p3.z); atomicAdd(&acc[d0][15], p3.w);
        atomicAdd(&acc[d1][0],  q0.x); atomicAdd(&acc[d1][1],  q0.y);
        atomicAdd(&acc[d1][2],  q0.z); atomicAdd(&acc[d1][3],  q0.w);
        atomicAdd(&acc[d1][4],  q1.x); atomicAdd(&acc[d1][5],  q1.y);
        atomicAdd(&acc[d1][6],  q1.z); atomicAdd(&acc[d1][7],  q1.w);
        atomicAdd(&acc[d1][8],  q2.x); atomicAdd(&acc[d1][9],  q2.y);
        atomicAdd(&acc[d1][10], q2.z); atomicAdd(&acc[d1][11], q2.w);
        atomicAdd(&acc[d1][12], q3.x); atomicAdd(&acc[d1][13], q3.y);
        atomicAdd(&acc[d1][14], q3.z); atomicAdd(&acc[d1][15], q3.w);
    }
    if (e < end) {
        unsigned r = recs[e];
        int s = r & SRCMASK;
        int dl = r >> PSHIFT;
        size_t sb = (size_t)s * 4;
        float4 p0 = y[sb + 0], p1 = y[sb + 1], p2 = y[sb + 2], p3 = y[sb + 3];
        atomicAdd(&acc[dl][0],  p0.x); atomicAdd(&acc[dl][1],  p0.y);
        atomicAdd(&acc[dl][2],  p0.z); atomicAdd(&acc[dl][3],  p0.w);
        atomicAdd(&acc[dl][4],  p1.x); atomicAdd(&acc[dl][5],  p1.y);
        atomicAdd(&acc[dl][6],  p1.z); atomicAdd(&acc[dl][7],  p1.w);
        atomicAdd(&acc[dl][8],  p2.x); atomicAdd(&acc[dl][9],  p2.y);
        atomicAdd(&acc[dl][10], p2.z); atomicAdd(&acc[dl][11], p2.w);
        atomicAdd(&acc[dl][12], p3.x); atomicAdd(&acc[dl][13], p3.y);
        atomicAdd(&acc[dl][14], p3.z); atomicAdd(&acc[dl][15], p3.w);
    }
    __syncthreads();

    int node = b * WB + t;
    if (t >= WB || node >= NNODES) return;

    float di = dinv[node];
    size_t yb = (size_t)node * 4;
    float4 s0 = y[yb + 0], s1 = y[yb + 1], s2 = y[yb + 2], s3 = y[yb + 3];
    float self[FH2] = {s0.x, s0.y, s0.z, s0.w, s1.x, s1.y, s1.z, s1.w,
                       s2.x, s2.y, s2.z, s2.w, s3.x, s3.y, s3.z, s3.w};

    float o0 = sbfc[0], o1 = sbfc[1];
#pragma unroll
    for (int k = 0; k < FH2; ++k) {
        float h = fmaxf(fmaf(di, acc[t][k] + self[k], sb2[k]), 0.0f);
        o0 = fmaf(h, sWfc[k * NC + 0], o0);
        o1 = fmaf(h, sWfc[k * NC + 1], o1);
    }
    float2 ov; ov.x = o0; ov.y = o1;
    out[node] = ov;
}

// ---------------- launch ----------------

extern "C" void kernel_launch(void* const* d_in, const int* in_sizes, int n_in,
                              void* d_out, int out_size, void* d_ws, size_t ws_size,
                              hipStream_t stream) {
    const float* x   = (const float*)d_in[0];
    const int*   ei  = (const int*)d_in[1];
    const float* W1  = (const float*)d_in[2];
    const float* b1  = (const float*)d_in[3];
    const float* W2  = (const float*)d_in[4];
    const float* b2  = (const float*)d_in[5];
    const float* Wfc = (const float*)d_in[6];
    const float* bfc = (const float*)d_in[7];
    float* out = (float*)d_out;

    char* p = (char*)d_ws;
    auto carve = [&](size_t bytes) -> char* {
        char* r = p;
        p += (bytes + 255) & ~(size_t)255;
        return r;
    };
    int*      counts = (int*)carve((size_t)NKEY * 4);
    int*      offs   = (int*)carve((size_t)NKEY * 4);
    int*      cur    = (int*)carve((size_t)NKEY * 4);
    float*    dinv   = (float*)carve((size_t)NNODES * 4);
    float*    gx     = (float*)carve((size_t)NNODES * 8 * 4);
    float*    y      = (float*)carve((size_t)NNODES * 16 * 4);
    unsigned* recs   = (unsigned*)carve((size_t)NEDGES * 4);
    // total ~44.6 MB (below the proven 48.9 MB round-0 footprint)

    int nblocks = (NNODES + 255) / 256;

    zero_counts<<<(NKEY + 255) / 256, 256, 0, stream>>>(counts);
    p1_count<<<NBLK_P1, 256, 0, stream>>>(ei, counts);
    scan_small<<<1, SCAN_T, 0, stream>>>(counts, offs, cur);
    p2_scatter<<<NBLK_P2, 256, 0, stream>>>(ei, cur, recs);
    p3_dinv<<<NBUCK, 256, 0, stream>>>(recs, offs, dinv);
    gx_kernel<<<nblocks, 256, 0, stream>>>(x, dinv, (float4*)gx);
    l1_bucket<<<NBUCK, 256, 0, stream>>>(recs, offs, (const float4*)gx, dinv,
                                         W1, b1, W2, (float4*)y);
    l2_bucket<<<NBUCK, 256, 0, stream>>>(recs, offs, (const float4*)y, dinv,
                                         b2, Wfc, bfc, (float2*)out);
}

// Round 3
// 1145.128 us; speedup vs baseline: 1.2715x; 1.2715x over previous
//
#include <hip/hip_runtime.h>

#define NNODES 200000
#define NEDGES 6400000
#define FIN 7
#define FH1 32
#define FH2 16
#define NC 2

// bucketing
#define WB 128                       // nodes per bucket
#define WB_SHIFT 7
#define NBUCK ((NNODES + WB - 1) / WB)   // 1563
#define NBLK 256                      // blocks for count/scatter passes
#define CHUNK ((NEDGES + NBLK - 1) / NBLK)  // 25000
#define PSHIFT 18
#define SRCMASK ((1u << PSHIFT) - 1)

// scan over counts[NBUCK][NBLK]
#define SCAN_N (NBUCK * NBLK)        // 400128
#define SCAN_ITEMS 16
#define SCAN_TILE (256 * SCAN_ITEMS) // 4096
#define SCAN_NT ((SCAN_N + SCAN_TILE - 1) / SCAN_TILE)  // 98

// ---------------- P1: per-block bucket histogram ----------------

__global__ __launch_bounds__(256) void p1_count(const int* __restrict__ ei,
                                                int* __restrict__ counts) {
    __shared__ int h[NBUCK];
    for (int i = threadIdx.x; i < NBUCK; i += 256) h[i] = 0;
    __syncthreads();
    int base = blockIdx.x * CHUNK;
    int end = base + CHUNK;
    if (end > NEDGES) end = NEDGES;
    for (int e = base + threadIdx.x; e < end; e += 256) {
        int d = ei[NEDGES + e];
        atomicAdd(&h[d >> WB_SHIFT], 1);
    }
    __syncthreads();
    for (int i = threadIdx.x; i < NBUCK; i += 256)
        counts[i * NBLK + blockIdx.x] = h[i];
}

// ---------------- scan (3 kernels) ----------------

__global__ __launch_bounds__(256) void scan_sums(const int* __restrict__ in,
                                                 int* __restrict__ part) {
    int base = blockIdx.x * SCAN_TILE + threadIdx.x * SCAN_ITEMS;
    int s = 0;
#pragma unroll
    for (int k = 0; k < SCAN_ITEMS; ++k) {
        int idx = base + k;
        if (idx < SCAN_N) s += in[idx];
    }
    __shared__ int sm[256];
    sm[threadIdx.x] = s;
    __syncthreads();
    for (int off = 128; off > 0; off >>= 1) {
        if (threadIdx.x < off) sm[threadIdx.x] += sm[threadIdx.x + off];
        __syncthreads();
    }
    if (threadIdx.x == 0) part[blockIdx.x] = sm[0];
}

__global__ void scan_top_g(int* __restrict__ part) {
    if (threadIdx.x == 0 && blockIdx.x == 0) {
        int acc = 0;
        for (int i = 0; i < SCAN_NT; ++i) {
            int v = part[i];
            part[i] = acc;
            acc += v;
        }
    }
}

__global__ __launch_bounds__(256) void scan_write_g(const int* __restrict__ in,
                                                    const int* __restrict__ part,
                                                    int* __restrict__ out) {
    int t = threadIdx.x;
    int base = blockIdx.x * SCAN_TILE + t * SCAN_ITEMS;
    int local[SCAN_ITEMS];
    int s = 0;
#pragma unroll
    for (int k = 0; k < SCAN_ITEMS; ++k) {
        int idx = base + k;
        int v = (idx < SCAN_N) ? in[idx] : 0;
        local[k] = v;
        s += v;
    }
    __shared__ int sm[256];
    sm[t] = s;
    __syncthreads();
    for (int off = 1; off < 256; off <<= 1) {
        int v = (t >= off) ? sm[t - off] : 0;
        __syncthreads();
        sm[t] += v;
        __syncthreads();
    }
    int prefix = part[blockIdx.x] + sm[t] - s;  // exclusive
#pragma unroll
    for (int k = 0; k < SCAN_ITEMS; ++k) {
        int idx = base + k;
        if (idx < SCAN_N) {
            out[idx] = prefix;
            prefix += local[k];
        }
    }
}

// ---------------- P2: scatter packed records into buckets ----------------

__global__ __launch_bounds__(256) void p2_scatter(const int* __restrict__ ei,
                                                  const int* __restrict__ offs,
                                                  unsigned int* __restrict__ recs) {
    __shared__ int cur[NBUCK];
    for (int i = threadIdx.x; i < NBUCK; i += 256)
        cur[i] = offs[i * NBLK + blockIdx.x];
    __syncthreads();
    int base = blockIdx.x * CHUNK;
    int end = base + CHUNK;
    if (end > NEDGES) end = NEDGES;
    for (int e = base + threadIdx.x; e < end; e += 256) {
        int s = ei[e];
        int d = ei[NEDGES + e];
        int b = d >> WB_SHIFT;
        int slot = atomicAdd(&cur[b], 1);
        recs[slot] = (unsigned)s | ((unsigned)(d & (WB - 1)) << PSHIFT);
    }
}

// ---------------- P3: per-bucket degree -> dinv ----------------

__global__ __launch_bounds__(256) void p3_dinv(const unsigned int* __restrict__ recs,
                                               const int* __restrict__ offs,
                                               float* __restrict__ dinv) {
    __shared__ int h[WB];
    int b = blockIdx.x;
    if (threadIdx.x < WB) h[threadIdx.x] = 0;
    __syncthreads();
    int beg = offs[b * NBLK];
    int end = (b + 1 < NBUCK) ? offs[(b + 1) * NBLK] : NEDGES;
    for (int e = beg + threadIdx.x; e < end; e += 256)
        atomicAdd(&h[recs[e] >> PSHIFT], 1);
    __syncthreads();
    int node = b * WB + threadIdx.x;
    if (threadIdx.x < WB && node < NNODES)
        dinv[node] = rsqrtf((float)(1 + h[threadIdx.x]));
}

// ---------------- gx = dinv * x, padded 7 -> 8 (pad lane = 0.0f) ----------------

__global__ __launch_bounds__(256) void gx_kernel(const float* __restrict__ x,
                                                 const float* __restrict__ dinv,
                                                 float4* __restrict__ gx) {
    int i = blockIdx.x * blockDim.x + threadIdx.x;
    if (i >= NNODES) return;
    float di = dinv[i];
    const float* xr = x + (size_t)i * FIN;
    float4 v0, v1;
    v0.x = xr[0] * di; v0.y = xr[1] * di; v0.z = xr[2] * di; v0.w = xr[3] * di;
    v1.x = xr[4] * di; v1.y = xr[5] * di; v1.z = xr[6] * di; v1.w = 0.0f;
    gx[(size_t)i * 2 + 0] = v0;
    gx[(size_t)i * 2 + 1] = v1;
}

// ---------------- L1: coalesced aggregate(gx) -> W1 -> relu -> W2 -> scale ----------------
// 2-lane group per edge: lane parity hq loads float4 half hq of the gx row.
// Consecutive lanes of a pair hit the SAME cache line -> TCP merges to one
// line transaction per edge (vs 2 scattered requests + rec before).

__global__ __launch_bounds__(256) void l1_bucket(const unsigned int* __restrict__ recs,
                                                 const int* __restrict__ offs,
                                                 const float4* __restrict__ gx,
                                                 const float* __restrict__ dinv,
                                                 const float* __restrict__ W1,
                                                 const float* __restrict__ b1,
                                                 const float* __restrict__ W2,
                                                 float4* __restrict__ y) {
    __shared__ float acc[WB][9];   // cols 0..6 real, 7 = pad (gx.w==0), 8 stride-pad
    __shared__ float sW1[FIN * FH1];
    __shared__ float sb1[FH1];
    __shared__ float sW2[FH1 * FH2];
    int t = threadIdx.x;
    for (int i = t; i < FIN * FH1; i += 256) sW1[i] = W1[i];
    if (t < FH1) sb1[t] = b1[t];
    for (int i = t; i < FH1 * FH2; i += 256) sW2[i] = W2[i];
    for (int i = t; i < WB * 9; i += 256) ((float*)acc)[i] = 0.0f;
    __syncthreads();

    int b = blockIdx.x;
    int beg = offs[b * NBLK];
    int end = (b + 1 < NBUCK) ? offs[(b + 1) * NBLK] : NEDGES;

    int hq = t & 1;            // which float4 half of the row
    int slot = t >> 1;         // 0..127 edge slot
    int kb = hq * 4;           // acc column base
    int e = beg + slot;
    for (; e + 3 * 128 < end; e += 4 * 128) {
        unsigned r0 = recs[e];
        unsigned r1 = recs[e + 128];
        unsigned r2 = recs[e + 256];
        unsigned r3 = recs[e + 384];
        int s0 = r0 & SRCMASK, d0 = r0 >> PSHIFT;
        int s1 = r1 & SRCMASK, d1 = r1 >> PSHIFT;
        int s2 = r2 & SRCMASK, d2 = r2 >> PSHIFT;
        int s3 = r3 & SRCMASK, d3 = r3 >> PSHIFT;
        float4 v0 = gx[(size_t)s0 * 2 + hq];
        float4 v1 = gx[(size_t)s1 * 2 + hq];
        float4 v2 = gx[(size_t)s2 * 2 + hq];
        float4 v3 = gx[(size_t)s3 * 2 + hq];
        atomicAdd(&acc[d0][kb + 0], v0.x); atomicAdd(&acc[d0][kb + 1], v0.y);
        atomicAdd(&acc[d0][kb + 2], v0.z); atomicAdd(&acc[d0][kb + 3], v0.w);
        atomicAdd(&acc[d1][kb + 0], v1.x); atomicAdd(&acc[d1][kb + 1], v1.y);
        atomicAdd(&acc[d1][kb + 2], v1.z); atomicAdd(&acc[d1][kb + 3], v1.w);
        atomicAdd(&acc[d2][kb + 0], v2.x); atomicAdd(&acc[d2][kb + 1], v2.y);
        atomicAdd(&acc[d2][kb + 2], v2.z); atomicAdd(&acc[d2][kb + 3], v2.w);
        atomicAdd(&acc[d3][kb + 0], v3.x); atomicAdd(&acc[d3][kb + 1], v3.y);
        atomicAdd(&acc[d3][kb + 2], v3.z); atomicAdd(&acc[d3][kb + 3], v3.w);
    }
    for (; e < end; e += 128) {
        unsigned r0 = recs[e];
        int s0 = r0 & SRCMASK, d0 = r0 >> PSHIFT;
        float4 v0 = gx[(size_t)s0 * 2 + hq];
        atomicAdd(&acc[d0][kb + 0], v0.x); atomicAdd(&acc[d0][kb + 1], v0.y);
        atomicAdd(&acc[d0][kb + 2], v0.z); atomicAdd(&acc[d0][kb + 3], v0.w);
    }
    __syncthreads();

    int node = b * WB + t;
    if (t >= WB || node >= NNODES) return;

    float di = dinv[node];
    float4 g0 = gx[(size_t)node * 2], g1 = gx[(size_t)node * 2 + 1];
    float xa[FIN];
    xa[0] = (acc[t][0] + g0.x) * di;
    xa[1] = (acc[t][1] + g0.y) * di;
    xa[2] = (acc[t][2] + g0.z) * di;
    xa[3] = (acc[t][3] + g0.w) * di;
    xa[4] = (acc[t][4] + g1.x) * di;
    xa[5] = (acc[t][5] + g1.y) * di;
    xa[6] = (acc[t][6] + g1.z) * di;

    float h1[FH1];
#pragma unroll
    for (int j = 0; j < FH1; ++j) h1[j] = sb1[j];
#pragma unroll
    for (int f = 0; f < FIN; ++f) {
        float xv = xa[f];
#pragma unroll
        for (int j = 0; j < FH1; ++j) h1[j] = fmaf(xv, sW1[f * FH1 + j], h1[j]);
    }
#pragma unroll
    for (int j = 0; j < FH1; ++j) h1[j] = fmaxf(h1[j], 0.0f);

    float yv[FH2];
#pragma unroll
    for (int j = 0; j < FH2; ++j) yv[j] = 0.0f;
#pragma unroll
    for (int k = 0; k < FH1; ++k) {
        float hv = h1[k];
#pragma unroll
        for (int j = 0; j < FH2; ++j) yv[j] = fmaf(hv, sW2[k * FH2 + j], yv[j]);
    }

    size_t yb = (size_t)node * 4;
    float4 o;
    o.x = yv[0] * di; o.y = yv[1] * di; o.z = yv[2] * di; o.w = yv[3] * di;
    y[yb + 0] = o;
    o.x = yv[4] * di; o.y = yv[5] * di; o.z = yv[6] * di; o.w = yv[7] * di;
    y[yb + 1] = o;
    o.x = yv[8] * di; o.y = yv[9] * di; o.z = yv[10] * di; o.w = yv[11] * di;
    y[yb + 2] = o;
    o.x = yv[12] * di; o.y = yv[13] * di; o.z = yv[14] * di; o.w = yv[15] * di;
    y[yb + 3] = o;
}

// ---------------- L2: coalesced aggregate(y) -> +b2 -> relu -> Wfc ----------------
// 4-lane group per edge: lane q loads float4 quarter q of the 64B y row.
// 4 consecutive lanes -> same cache line -> one merged transaction per edge
// (vs 4 scattered 16B requests before).

__global__ __launch_bounds__(256) void l2_bucket(const unsigned int* __restrict__ recs,
                                                 const int* __restrict__ offs,
                                                 const float4* __restrict__ y,
                                                 const float* __restrict__ dinv,
                                                 const float* __restrict__ b2,
                                                 const float* __restrict__ Wfc,
                                                 const float* __restrict__ bfc,
                                                 float2* __restrict__ out) {
    __shared__ float acc[WB][17];  // pad 16->17: break stride-16 bank pattern
    __shared__ float sb2[FH2];
    __shared__ float sWfc[FH2 * NC];
    __shared__ float sbfc[NC];
    int t = threadIdx.x;
    if (t < FH2) sb2[t] = b2[t];
    if (t < FH2 * NC) sWfc[t] = Wfc[t];
    if (t < NC) sbfc[t] = bfc[t];
    for (int i = t; i < WB * 17; i += 256) ((float*)acc)[i] = 0.0f;
    __syncthreads();

    int b = blockIdx.x;
    int beg = offs[b * NBLK];
    int end = (b + 1 < NBUCK) ? offs[(b + 1) * NBLK] : NEDGES;

    int q = t & 3;             // which float4 quarter of the row
    int slot = t >> 2;         // 0..63 edge slot
    int kb = q * 4;            // acc column base
    int e = beg + slot;
    for (; e + 3 * 64 < end; e += 4 * 64) {
        unsigned r0 = recs[e];
        unsigned r1 = recs[e + 64];
        unsigned r2 = recs[e + 128];
        unsigned r3 = recs[e + 192];
        int s0 = r0 & SRCMASK, d0 = r0 >> PSHIFT;
        int s1 = r1 & SRCMASK, d1 = r1 >> PSHIFT;
        int s2 = r2 & SRCMASK, d2 = r2 >> PSHIFT;
        int s3 = r3 & SRCMASK, d3 = r3 >> PSHIFT;
        float4 v0 = y[(size_t)s0 * 4 + q];
        float4 v1 = y[(size_t)s1 * 4 + q];
        float4 v2 = y[(size_t)s2 * 4 + q];
        float4 v3 = y[(size_t)s3 * 4 + q];
        atomicAdd(&acc[d0][kb + 0], v0.x); atomicAdd(&acc[d0][kb + 1], v0.y);
        atomicAdd(&acc[d0][kb + 2], v0.z); atomicAdd(&acc[d0][kb + 3], v0.w);
        atomicAdd(&acc[d1][kb + 0], v1.x); atomicAdd(&acc[d1][kb + 1], v1.y);
        atomicAdd(&acc[d1][kb + 2], v1.z); atomicAdd(&acc[d1][kb + 3], v1.w);
        atomicAdd(&acc[d2][kb + 0], v2.x); atomicAdd(&acc[d2][kb + 1], v2.y);
        atomicAdd(&acc[d2][kb + 2], v2.z); atomicAdd(&acc[d2][kb + 3], v2.w);
        atomicAdd(&acc[d3][kb + 0], v3.x); atomicAdd(&acc[d3][kb + 1], v3.y);
        atomicAdd(&acc[d3][kb + 2], v3.z); atomicAdd(&acc[d3][kb + 3], v3.w);
    }
    for (; e < end; e += 64) {
        unsigned r0 = recs[e];
        int s0 = r0 & SRCMASK, d0 = r0 >> PSHIFT;
        float4 v0 = y[(size_t)s0 * 4 + q];
        atomicAdd(&acc[d0][kb + 0], v0.x); atomicAdd(&acc[d0][kb + 1], v0.y);
        atomicAdd(&acc[d0][kb + 2], v0.z); atomicAdd(&acc[d0][kb + 3], v0.w);
    }
    __syncthreads();

    int node = b * WB + t;
    if (t >= WB || node >= NNODES) return;

    float di = dinv[node];
    size_t yb = (size_t)node * 4;
    float4 s0 = y[yb + 0], s1 = y[yb + 1], s2 = y[yb + 2], s3 = y[yb + 3];
    float self[FH2] = {s0.x, s0.y, s0.z, s0.w, s1.x, s1.y, s1.z, s1.w,
                       s2.x, s2.y, s2.z, s2.w, s3.x, s3.y, s3.z, s3.w};

    float o0 = sbfc[0], o1 = sbfc[1];
#pragma unroll
    for (int k = 0; k < FH2; ++k) {
        float h = fmaxf(fmaf(di, acc[t][k] + self[k], sb2[k]), 0.0f);
        o0 = fmaf(h, sWfc[k * NC + 0], o0);
        o1 = fmaf(h, sWfc[k * NC + 1], o1);
    }
    float2 ov; ov.x = o0; ov.y = o1;
    out[node] = ov;
}

// ---------------- launch ----------------

extern "C" void kernel_launch(void* const* d_in, const int* in_sizes, int n_in,
                              void* d_out, int out_size, void* d_ws, size_t ws_size,
                              hipStream_t stream) {
    const float* x   = (const float*)d_in[0];
    const int*   ei  = (const int*)d_in[1];
    const float* W1  = (const float*)d_in[2];
    const float* b1  = (const float*)d_in[3];
    const float* W2  = (const float*)d_in[4];
    const float* b2  = (const float*)d_in[5];
    const float* Wfc = (const float*)d_in[6];
    const float* bfc = (const float*)d_in[7];
    float* out = (float*)d_out;

    char* p = (char*)d_ws;
    auto carve = [&](size_t bytes) -> char* {
        char* r = p;
        p += (bytes + 255) & ~(size_t)255;
        return r;
    };
    int*      counts = (int*)carve((size_t)SCAN_N * 4);
    int*      offs   = (int*)carve((size_t)SCAN_N * 4);
    int*      part   = (int*)carve(128 * 4);
    float*    dinv   = (float*)carve((size_t)NNODES * 4);
    float*    gx     = (float*)carve((size_t)NNODES * 8 * 4);
    float*    y      = (float*)carve((size_t)NNODES * 16 * 4);
    unsigned* recs   = (unsigned*)carve((size_t)NEDGES * 4);
    // total ~48.9 MB (identical to the proven round-0 footprint)

    int nblocks = (NNODES + 255) / 256;

    p1_count<<<NBLK, 256, 0, stream>>>(ei, counts);
    scan_sums<<<SCAN_NT, 256, 0, stream>>>(counts, part);
    scan_top_g<<<1, 64, 0, stream>>>(part);
    scan_write_g<<<SCAN_NT, 256, 0, stream>>>(counts, part, offs);
    p2_scatter<<<NBLK, 256, 0, stream>>>(ei, offs, recs);
    p3_dinv<<<NBUCK, 256, 0, stream>>>(recs, offs, dinv);
    gx_kernel<<<nblocks, 256, 0, stream>>>(x, dinv, (float4*)gx);
    l1_bucket<<<NBUCK, 256, 0, stream>>>(recs, offs, (const float4*)gx, dinv,
                                         W1, b1, W2, (float4*)y);
    l2_bucket<<<NBUCK, 256, 0, stream>>>(recs, offs, (const float4*)y, dinv,
                                         b2, Wfc, bfc, (float2*)out);
}

// Round 4
// 1110.613 us; speedup vs baseline: 1.3111x; 1.0311x over previous
//
#include <hip/hip_runtime.h>

#define NNODES 200000
#define NEDGES 6400000
#define FIN 7
#define FH1 32
#define FH2 16
#define NC 2

// CSR sort-by-destination
// l1: 128 nodes/block, 2 lanes per node. l2: 64 nodes/block, 4 lanes per node.
#define L1_NODES 128
#define L1_GRID ((NNODES + L1_NODES - 1) / L1_NODES)   // 1563
#define L2_NODES 64
#define L2_GRID ((NNODES + L2_NODES - 1) / L2_NODES)   // 3125

// grid-stride passes over edges
#define EBLK 1024
#define ESTRIDE (EBLK * 256)

// scan over deg[NNODES]
#define SCAN_ITEMS 16
#define SCAN_TILE (256 * SCAN_ITEMS)                   // 4096
#define SCAN_NT ((NNODES + SCAN_TILE - 1) / SCAN_TILE) // 49

// ---------------- zero degree array ----------------

__global__ __launch_bounds__(256) void zero_deg(int* __restrict__ deg) {
    int i = blockIdx.x * 256 + threadIdx.x;
    if (i < NNODES) deg[i] = 0;
}

// ---------------- P1: per-node in-degree via global atomics ----------------

__global__ __launch_bounds__(256) void p1_deg(const int* __restrict__ ei,
                                              int* __restrict__ deg) {
    int i = blockIdx.x * 256 + threadIdx.x;
    for (int e = i; e < NEDGES; e += ESTRIDE)
        atomicAdd(&deg[ei[NEDGES + e]], 1);
}

// ---------------- scan deg -> node_off (exclusive), cur = copy ----------------

__global__ __launch_bounds__(256) void scan_sums(const int* __restrict__ in,
                                                 int* __restrict__ part) {
    int base = blockIdx.x * SCAN_TILE + threadIdx.x * SCAN_ITEMS;
    int s = 0;
#pragma unroll
    for (int k = 0; k < SCAN_ITEMS; ++k) {
        int idx = base + k;
        if (idx < NNODES) s += in[idx];
    }
    __shared__ int sm[256];
    sm[threadIdx.x] = s;
    __syncthreads();
    for (int off = 128; off > 0; off >>= 1) {
        if (threadIdx.x < off) sm[threadIdx.x] += sm[threadIdx.x + off];
        __syncthreads();
    }
    if (threadIdx.x == 0) part[blockIdx.x] = sm[0];
}

__global__ void scan_top_g(int* __restrict__ part) {
    if (threadIdx.x == 0 && blockIdx.x == 0) {
        int acc = 0;
        for (int i = 0; i < SCAN_NT; ++i) {
            int v = part[i];
            part[i] = acc;
            acc += v;
        }
    }
}

__global__ __launch_bounds__(256) void scan_write_g(const int* __restrict__ in,
                                                    const int* __restrict__ part,
                                                    int* __restrict__ node_off,
                                                    int* __restrict__ cur) {
    int t = threadIdx.x;
    int base = blockIdx.x * SCAN_TILE + t * SCAN_ITEMS;
    int local[SCAN_ITEMS];
    int s = 0;
#pragma unroll
    for (int k = 0; k < SCAN_ITEMS; ++k) {
        int idx = base + k;
        int v = (idx < NNODES) ? in[idx] : 0;
        local[k] = v;
        s += v;
    }
    __shared__ int sm[256];
    sm[t] = s;
    __syncthreads();
    for (int off = 1; off < 256; off <<= 1) {
        int v = (t >= off) ? sm[t - off] : 0;
        __syncthreads();
        sm[t] += v;
        __syncthreads();
    }
    int prefix = part[blockIdx.x] + sm[t] - s;  // exclusive
#pragma unroll
    for (int k = 0; k < SCAN_ITEMS; ++k) {
        int idx = base + k;
        if (idx < NNODES) {
            node_off[idx] = prefix;
            cur[idx] = prefix;
            prefix += local[k];
        }
    }
    if (blockIdx.x == 0 && t == 0) node_off[NNODES] = NEDGES;
}

// ---------------- P2: scatter src into dst-sorted order (CSR) ----------------

__global__ __launch_bounds__(256) void p2_scatter(const int* __restrict__ ei,
                                                  int* __restrict__ cur,
                                                  int* __restrict__ recs) {
    int i = blockIdx.x * 256 + threadIdx.x;
    for (int e = i; e < NEDGES; e += ESTRIDE) {
        int s = ei[e];
        int d = ei[NEDGES + e];
        int slot = atomicAdd(&cur[d], 1);
        recs[slot] = s;
    }
}

// ---------------- dinv = rsqrt(deg + 1) ----------------

__global__ __launch_bounds__(256) void p_dinv(const int* __restrict__ deg,
                                              float* __restrict__ dinv) {
    int i = blockIdx.x * 256 + threadIdx.x;
    if (i < NNODES) dinv[i] = rsqrtf((float)(1 + deg[i]));
}

// ---------------- gx = dinv * x, padded 7 -> 8 (pad lane = 0.0f) ----------------

__global__ __launch_bounds__(256) void gx_kernel(const float* __restrict__ x,
                                                 const float* __restrict__ dinv,
                                                 float4* __restrict__ gx) {
    int i = blockIdx.x * blockDim.x + threadIdx.x;
    if (i >= NNODES) return;
    float di = dinv[i];
    const float* xr = x + (size_t)i * FIN;
    float4 v0, v1;
    v0.x = xr[0] * di; v0.y = xr[1] * di; v0.z = xr[2] * di; v0.w = xr[3] * di;
    v1.x = xr[4] * di; v1.y = xr[5] * di; v1.z = xr[6] * di; v1.w = 0.0f;
    gx[(size_t)i * 2 + 0] = v0;
    gx[(size_t)i * 2 + 1] = v1;
}

// ---------------- L1: CSR segmented reduce (NO atomics) -> W1 -> relu -> W2 ----------------
// 2 lanes per node: lane hq accumulates float4 half hq of the gx row in REGISTERS.

__global__ __launch_bounds__(256) void l1_csr(const int* __restrict__ recs,
                                              const int* __restrict__ node_off,
                                              const float4* __restrict__ gx,
                                              const float* __restrict__ dinv,
                                              const float* __restrict__ W1,
                                              const float* __restrict__ b1,
                                              const float* __restrict__ W2,
                                              float4* __restrict__ y) {
    __shared__ float acc[L1_NODES][9];   // cols 0..7 written, 8 = stride pad
    __shared__ float sW1[FIN * FH1];
    __shared__ float sb1[FH1];
    __shared__ float sW2[FH1 * FH2];
    int t = threadIdx.x;
    for (int i = t; i < FIN * FH1; i += 256) sW1[i] = W1[i];
    if (t < FH1) sb1[t] = b1[t];
    for (int i = t; i < FH1 * FH2; i += 256) sW2[i] = W2[i];

    int n = t >> 1;
    int hq = t & 1;
    int node = blockIdx.x * L1_NODES + n;
    float4 a = {0.0f, 0.0f, 0.0f, 0.0f};
    if (node < NNODES) {
        int beg = node_off[node];
        int end = node_off[node + 1];
        int e = beg;
        for (; e + 3 < end; e += 4) {
            int s0 = recs[e], s1 = recs[e + 1], s2 = recs[e + 2], s3 = recs[e + 3];
            float4 v0 = gx[(size_t)s0 * 2 + hq];
            float4 v1 = gx[(size_t)s1 * 2 + hq];
            float4 v2 = gx[(size_t)s2 * 2 + hq];
            float4 v3 = gx[(size_t)s3 * 2 + hq];
            a.x += v0.x + v1.x; a.y += v0.y + v1.y;
            a.z += v0.z + v1.z; a.w += v0.w + v1.w;
            a.x += v2.x + v3.x; a.y += v2.y + v3.y;
            a.z += v2.z + v3.z; a.w += v2.w + v3.w;
        }
        for (; e < end; ++e) {
            int s0 = recs[e];
            float4 v0 = gx[(size_t)s0 * 2 + hq];
            a.x += v0.x; a.y += v0.y; a.z += v0.z; a.w += v0.w;
        }
    }
    int kb = hq * 4;
    acc[n][kb + 0] = a.x; acc[n][kb + 1] = a.y;
    acc[n][kb + 2] = a.z; acc[n][kb + 3] = a.w;
    __syncthreads();

    node = blockIdx.x * L1_NODES + t;
    if (t >= L1_NODES || node >= NNODES) return;

    float di = dinv[node];
    float4 g0 = gx[(size_t)node * 2], g1 = gx[(size_t)node * 2 + 1];
    float xa[FIN];
    xa[0] = (acc[t][0] + g0.x) * di;
    xa[1] = (acc[t][1] + g0.y) * di;
    xa[2] = (acc[t][2] + g0.z) * di;
    xa[3] = (acc[t][3] + g0.w) * di;
    xa[4] = (acc[t][4] + g1.x) * di;
    xa[5] = (acc[t][5] + g1.y) * di;
    xa[6] = (acc[t][6] + g1.z) * di;

    float h1[FH1];
#pragma unroll
    for (int j = 0; j < FH1; ++j) h1[j] = sb1[j];
#pragma unroll
    for (int f = 0; f < FIN; ++f) {
        float xv = xa[f];
#pragma unroll
        for (int j = 0; j < FH1; ++j) h1[j] = fmaf(xv, sW1[f * FH1 + j], h1[j]);
    }
#pragma unroll
    for (int j = 0; j < FH1; ++j) h1[j] = fmaxf(h1[j], 0.0f);

    float yv[FH2];
#pragma unroll
    for (int j = 0; j < FH2; ++j) yv[j] = 0.0f;
#pragma unroll
    for (int k = 0; k < FH1; ++k) {
        float hv = h1[k];
#pragma unroll
        for (int j = 0; j < FH2; ++j) yv[j] = fmaf(hv, sW2[k * FH2 + j], yv[j]);
    }

    size_t yb = (size_t)node * 4;
    float4 o;
    o.x = yv[0] * di; o.y = yv[1] * di; o.z = yv[2] * di; o.w = yv[3] * di;
    y[yb + 0] = o;
    o.x = yv[4] * di; o.y = yv[5] * di; o.z = yv[6] * di; o.w = yv[7] * di;
    y[yb + 1] = o;
    o.x = yv[8] * di; o.y = yv[9] * di; o.z = yv[10] * di; o.w = yv[11] * di;
    y[yb + 2] = o;
    o.x = yv[12] * di; o.y = yv[13] * di; o.z = yv[14] * di; o.w = yv[15] * di;
    y[yb + 3] = o;
}

// ---------------- L2: CSR segmented reduce (NO atomics) -> +b2 -> relu -> Wfc ----------------
// 4 lanes per node: lane q accumulates float4 quarter q of the 64B y row in REGISTERS.

__global__ __launch_bounds__(256) void l2_csr(const int* __restrict__ recs,
                                              const int* __restrict__ node_off,
                                              const float4* __restrict__ y,
                                              const float* __restrict__ dinv,
                                              const float* __restrict__ b2,
                                              const float* __restrict__ Wfc,
                                              const float* __restrict__ bfc,
                                              float2* __restrict__ out) {
    __shared__ float acc[L2_NODES][17];  // 16 cols + stride pad
    __shared__ float sb2[FH2];
    __shared__ float sWfc[FH2 * NC];
    __shared__ float sbfc[NC];
    int t = threadIdx.x;
    if (t < FH2) sb2[t] = b2[t];
    if (t < FH2 * NC) sWfc[t] = Wfc[t];
    if (t < NC) sbfc[t] = bfc[t];

    int n = t >> 2;
    int q = t & 3;
    int node = blockIdx.x * L2_NODES + n;   // grid covers exactly NNODES
    int beg = node_off[node];
    int end = node_off[node + 1];
    float4 a = {0.0f, 0.0f, 0.0f, 0.0f};
    int e = beg;
    for (; e + 3 < end; e += 4) {
        int s0 = recs[e], s1 = recs[e + 1], s2 = recs[e + 2], s3 = recs[e + 3];
        float4 v0 = y[(size_t)s0 * 4 + q];
        float4 v1 = y[(size_t)s1 * 4 + q];
        float4 v2 = y[(size_t)s2 * 4 + q];
        float4 v3 = y[(size_t)s3 * 4 + q];
        a.x += v0.x + v1.x; a.y += v0.y + v1.y;
        a.z += v0.z + v1.z; a.w += v0.w + v1.w;
        a.x += v2.x + v3.x; a.y += v2.y + v3.y;
        a.z += v2.z + v3.z; a.w += v2.w + v3.w;
    }
    for (; e < end; ++e) {
        int s0 = recs[e];
        float4 v0 = y[(size_t)s0 * 4 + q];
        a.x += v0.x; a.y += v0.y; a.z += v0.z; a.w += v0.w;
    }
    int kb = q * 4;
    acc[n][kb + 0] = a.x; acc[n][kb + 1] = a.y;
    acc[n][kb + 2] = a.z; acc[n][kb + 3] = a.w;
    __syncthreads();

    if (t >= L2_NODES) return;
    node = blockIdx.x * L2_NODES + t;

    float di = dinv[node];
    size_t yb = (size_t)node * 4;
    float4 s0 = y[yb + 0], s1 = y[yb + 1], s2 = y[yb + 2], s3 = y[yb + 3];
    float self[FH2] = {s0.x, s0.y, s0.z, s0.w, s1.x, s1.y, s1.z, s1.w,
                       s2.x, s2.y, s2.z, s2.w, s3.x, s3.y, s3.z, s3.w};

    float o0 = sbfc[0], o1 = sbfc[1];
#pragma unroll
    for (int k = 0; k < FH2; ++k) {
        float h = fmaxf(fmaf(di, acc[t][k] + self[k], sb2[k]), 0.0f);
        o0 = fmaf(h, sWfc[k * NC + 0], o0);
        o1 = fmaf(h, sWfc[k * NC + 1], o1);
    }
    float2 ov; ov.x = o0; ov.y = o1;
    out[node] = ov;
}

// ---------------- launch ----------------

extern "C" void kernel_launch(void* const* d_in, const int* in_sizes, int n_in,
                              void* d_out, int out_size, void* d_ws, size_t ws_size,
                              hipStream_t stream) {
    const float* x   = (const float*)d_in[0];
    const int*   ei  = (const int*)d_in[1];
    const float* W1  = (const float*)d_in[2];
    const float* b1  = (const float*)d_in[3];
    const float* W2  = (const float*)d_in[4];
    const float* b2  = (const float*)d_in[5];
    const float* Wfc = (const float*)d_in[6];
    const float* bfc = (const float*)d_in[7];
    float* out = (float*)d_out;

    char* p = (char*)d_ws;
    auto carve = [&](size_t bytes) -> char* {
        char* r = p;
        p += (bytes + 255) & ~(size_t)255;
        return r;
    };
    int*   deg      = (int*)carve((size_t)NNODES * 4);
    int*   node_off = (int*)carve((size_t)(NNODES + 1) * 4);
    int*   cur      = (int*)carve((size_t)NNODES * 4);
    int*   part     = (int*)carve(64 * 4);
    float* dinv     = (float*)carve((size_t)NNODES * 4);
    float* gx       = (float*)carve((size_t)NNODES * 8 * 4);
    float* y        = (float*)carve((size_t)NNODES * 16 * 4);
    int*   recs     = (int*)carve((size_t)NEDGES * 4);
    // total ~48.0 MB (below the proven 48.9 MB footprint)

    int nblocks = (NNODES + 255) / 256;

    zero_deg<<<nblocks, 256, 0, stream>>>(deg);
    p1_deg<<<EBLK, 256, 0, stream>>>(ei, deg);
    scan_sums<<<SCAN_NT, 256, 0, stream>>>(deg, part);
    scan_top_g<<<1, 64, 0, stream>>>(part);
    scan_write_g<<<SCAN_NT, 256, 0, stream>>>(deg, part, node_off, cur);
    p2_scatter<<<EBLK, 256, 0, stream>>>(ei, cur, recs);
    p_dinv<<<nblocks, 256, 0, stream>>>(deg, dinv);
    gx_kernel<<<nblocks, 256, 0, stream>>>(x, dinv, (float4*)gx);
    l1_csr<<<L1_GRID, 256, 0, stream>>>(recs, node_off, (const float4*)gx, dinv,
                                        W1, b1, W2, (float4*)y);
    l2_csr<<<L2_GRID, 256, 0, stream>>>(recs, node_off, (const float4*)y, dinv,
                                        b2, Wfc, bfc, (float2*)out);
}

// Round 5
// 419.077 us; speedup vs baseline: 3.4745x; 2.6501x over previous
//
#include <hip/hip_runtime.h>

#define NNODES 200000
#define NEDGES 6400000
#define FIN 7
#define FH1 32
#define FH2 16
#define NC 2

// bucketing (round-0 proven machinery)
#define WB 128                       // nodes per bucket
#define WB_SHIFT 7
#define NBUCK ((NNODES + WB - 1) / WB)   // 1563
#define NBLK 256                      // blocks for count/scatter passes
#define CHUNK ((NEDGES + NBLK - 1) / NBLK)  // 25000
#define PSHIFT 18
#define SRCMASK ((1u << PSHIFT) - 1)

// per-bucket LDS CSR capacity: Poisson(4095) max over 1563 buckets ~ 4400; 16-sigma margin
#define SCAP 5120

// scan over counts[NBUCK][NBLK]
#define SCAN_N (NBUCK * NBLK)        // 400128
#define SCAN_ITEMS 16
#define SCAN_TILE (256 * SCAN_ITEMS) // 4096
#define SCAN_NT ((SCAN_N + SCAN_TILE - 1) / SCAN_TILE)  // 98

// ---------------- P1: per-block bucket histogram ----------------

__global__ __launch_bounds__(256) void p1_count(const int* __restrict__ ei,
                                                int* __restrict__ counts) {
    __shared__ int h[NBUCK];
    for (int i = threadIdx.x; i < NBUCK; i += 256) h[i] = 0;
    __syncthreads();
    int base = blockIdx.x * CHUNK;
    int end = base + CHUNK;
    if (end > NEDGES) end = NEDGES;
    for (int e = base + threadIdx.x; e < end; e += 256) {
        int d = ei[NEDGES + e];
        atomicAdd(&h[d >> WB_SHIFT], 1);
    }
    __syncthreads();
    for (int i = threadIdx.x; i < NBUCK; i += 256)
        counts[i * NBLK + blockIdx.x] = h[i];
}

// ---------------- scan (3 kernels) ----------------

__global__ __launch_bounds__(256) void scan_sums(const int* __restrict__ in,
                                                 int* __restrict__ part) {
    int base = blockIdx.x * SCAN_TILE + threadIdx.x * SCAN_ITEMS;
    int s = 0;
#pragma unroll
    for (int k = 0; k < SCAN_ITEMS; ++k) {
        int idx = base + k;
        if (idx < SCAN_N) s += in[idx];
    }
    __shared__ int sm[256];
    sm[threadIdx.x] = s;
    __syncthreads();
    for (int off = 128; off > 0; off >>= 1) {
        if (threadIdx.x < off) sm[threadIdx.x] += sm[threadIdx.x + off];
        __syncthreads();
    }
    if (threadIdx.x == 0) part[blockIdx.x] = sm[0];
}

__global__ void scan_top_g(int* __restrict__ part) {
    if (threadIdx.x == 0 && blockIdx.x == 0) {
        int acc = 0;
        for (int i = 0; i < SCAN_NT; ++i) {
            int v = part[i];
            part[i] = acc;
            acc += v;
        }
    }
}

__global__ __launch_bounds__(256) void scan_write_g(const int* __restrict__ in,
                                                    const int* __restrict__ part,
                                                    int* __restrict__ out) {
    int t = threadIdx.x;
    int base = blockIdx.x * SCAN_TILE + t * SCAN_ITEMS;
    int local[SCAN_ITEMS];
    int s = 0;
#pragma unroll
    for (int k = 0; k < SCAN_ITEMS; ++k) {
        int idx = base + k;
        int v = (idx < SCAN_N) ? in[idx] : 0;
        local[k] = v;
        s += v;
    }
    __shared__ int sm[256];
    sm[t] = s;
    __syncthreads();
    for (int off = 1; off < 256; off <<= 1) {
        int v = (t >= off) ? sm[t - off] : 0;
        __syncthreads();
        sm[t] += v;
        __syncthreads();
    }
    int prefix = part[blockIdx.x] + sm[t] - s;  // exclusive
#pragma unroll
    for (int k = 0; k < SCAN_ITEMS; ++k) {
        int idx = base + k;
        if (idx < SCAN_N) {
            out[idx] = prefix;
            prefix += local[k];
        }
    }
}

// ---------------- P2: scatter packed records into buckets (coalesced slices) ----------------

__global__ __launch_bounds__(256) void p2_scatter(const int* __restrict__ ei,
                                                  const int* __restrict__ offs,
                                                  unsigned int* __restrict__ recs) {
    __shared__ int cur[NBUCK];
    for (int i = threadIdx.x; i < NBUCK; i += 256)
        cur[i] = offs[i * NBLK + blockIdx.x];
    __syncthreads();
    int base = blockIdx.x * CHUNK;
    int end = base + CHUNK;
    if (end > NEDGES) end = NEDGES;
    for (int e = base + threadIdx.x; e < end; e += 256) {
        int s = ei[e];
        int d = ei[NEDGES + e];
        int b = d >> WB_SHIFT;
        int slot = atomicAdd(&cur[b], 1);
        recs[slot] = (unsigned)s | ((unsigned)(d & (WB - 1)) << PSHIFT);
    }
}

// ---------------- P3: per-bucket degree -> dinv ----------------

__global__ __launch_bounds__(256) void p3_dinv(const unsigned int* __restrict__ recs,
                                               const int* __restrict__ offs,
                                               float* __restrict__ dinv) {
    __shared__ int h[WB];
    int b = blockIdx.x;
    if (threadIdx.x < WB) h[threadIdx.x] = 0;
    __syncthreads();
    int beg = offs[b * NBLK];
    int end = (b + 1 < NBUCK) ? offs[(b + 1) * NBLK] : NEDGES;
    for (int e = beg + threadIdx.x; e < end; e += 256)
        atomicAdd(&h[recs[e] >> PSHIFT], 1);
    __syncthreads();
    int node = b * WB + threadIdx.x;
    if (threadIdx.x < WB && node < NNODES)
        dinv[node] = rsqrtf((float)(1 + h[threadIdx.x]));
}

// ---------------- gx = dinv * x, padded 7 -> 8 (pad lane = 0.0f) ----------------

__global__ __launch_bounds__(256) void gx_kernel(const float* __restrict__ x,
                                                 const float* __restrict__ dinv,
                                                 float4* __restrict__ gx) {
    int i = blockIdx.x * blockDim.x + threadIdx.x;
    if (i >= NNODES) return;
    float di = dinv[i];
    const float* xr = x + (size_t)i * FIN;
    float4 v0, v1;
    v0.x = xr[0] * di; v0.y = xr[1] * di; v0.z = xr[2] * di; v0.w = xr[3] * di;
    v1.x = xr[4] * di; v1.y = xr[5] * di; v1.z = xr[6] * di; v1.w = 0.0f;
    gx[(size_t)i * 2 + 0] = v0;
    gx[(size_t)i * 2 + 1] = v1;
}

// ---------------- L1: in-LDS CSR sort -> register segmented reduce -> W1 -> relu -> W2 ----------------

__global__ __launch_bounds__(256) void l1_sorted(const unsigned int* __restrict__ recs,
                                                 const int* __restrict__ offs,
                                                 const float4* __restrict__ gx,
                                                 const float* __restrict__ dinv,
                                                 const float* __restrict__ W1,
                                                 const float* __restrict__ b1,
                                                 const float* __restrict__ W2,
                                                 float4* __restrict__ y) {
    __shared__ int sl_src[SCAP];
    __shared__ int hist[WB], st[WB], cur[WB];
    __shared__ float acc[WB][9];
    __shared__ float sW1[FIN * FH1];
    __shared__ float sb1[FH1];
    __shared__ float sW2[FH1 * FH2];
    int t = threadIdx.x;
    for (int i = t; i < FIN * FH1; i += 256) sW1[i] = W1[i];
    if (t < FH1) sb1[t] = b1[t];
    for (int i = t; i < FH1 * FH2; i += 256) sW2[i] = W2[i];
    if (t < WB) hist[t] = 0;
    __syncthreads();

    int b = blockIdx.x;
    int beg = offs[b * NBLK];
    int end = (b + 1 < NBUCK) ? offs[(b + 1) * NBLK] : NEDGES;

    // pass A: local-destination histogram
    for (int e = beg + t; e < end; e += 256)
        atomicAdd(&hist[recs[e] >> PSHIFT], 1);
    __syncthreads();

    // exclusive scan of hist[128] (Hillis-Steele, uniform barriers)
    if (t < WB) cur[t] = hist[t];
    __syncthreads();
    for (int off = 1; off < WB; off <<= 1) {
        int v = 0;
        if (t < WB && t >= off) v = cur[t - off];
        __syncthreads();
        if (t < WB) cur[t] += v;
        __syncthreads();
    }
    if (t < WB) {
        st[t] = cur[t] - hist[t];
        cur[t] = cur[t] - hist[t];
    }
    __syncthreads();

    // pass B: scatter src into LDS CSR (records L2-warm from pass A)
    for (int e = beg + t; e < end; e += 256) {
        unsigned r = recs[e];
        int slot = atomicAdd(&cur[r >> PSHIFT], 1);
        sl_src[slot] = (int)(r & SRCMASK);
    }
    __syncthreads();

    // segmented reduce: 2 lanes per node, accumulate in registers (NO atomics)
    int n = t >> 1;
    int hq = t & 1;
    int cnt = hist[n];
    int base = st[n];
    float ax = 0.0f, ay = 0.0f, az = 0.0f, aw = 0.0f;
    int k = 0;
    for (; k + 3 < cnt; k += 4) {
        int s0 = sl_src[base + k];
        int s1 = sl_src[base + k + 1];
        int s2 = sl_src[base + k + 2];
        int s3 = sl_src[base + k + 3];
        float4 v0 = gx[(size_t)s0 * 2 + hq];
        float4 v1 = gx[(size_t)s1 * 2 + hq];
        float4 v2 = gx[(size_t)s2 * 2 + hq];
        float4 v3 = gx[(size_t)s3 * 2 + hq];
        ax += v0.x + v1.x; ay += v0.y + v1.y;
        az += v0.z + v1.z; aw += v0.w + v1.w;
        ax += v2.x + v3.x; ay += v2.y + v3.y;
        az += v2.z + v3.z; aw += v2.w + v3.w;
    }
    for (; k < cnt; ++k) {
        int s0 = sl_src[base + k];
        float4 v0 = gx[(size_t)s0 * 2 + hq];
        ax += v0.x; ay += v0.y; az += v0.z; aw += v0.w;
    }
    int kb = hq * 4;
    acc[n][kb + 0] = ax; acc[n][kb + 1] = ay;
    acc[n][kb + 2] = az; acc[n][kb + 3] = aw;
    __syncthreads();

    int node = b * WB + t;
    if (t >= WB || node >= NNODES) return;

    float di = dinv[node];
    float4 g0 = gx[(size_t)node * 2], g1 = gx[(size_t)node * 2 + 1];
    float xa[FIN];
    xa[0] = (acc[t][0] + g0.x) * di;
    xa[1] = (acc[t][1] + g0.y) * di;
    xa[2] = (acc[t][2] + g0.z) * di;
    xa[3] = (acc[t][3] + g0.w) * di;
    xa[4] = (acc[t][4] + g1.x) * di;
    xa[5] = (acc[t][5] + g1.y) * di;
    xa[6] = (acc[t][6] + g1.z) * di;

    float h1[FH1];
#pragma unroll
    for (int j = 0; j < FH1; ++j) h1[j] = sb1[j];
#pragma unroll
    for (int f = 0; f < FIN; ++f) {
        float xv = xa[f];
#pragma unroll
        for (int j = 0; j < FH1; ++j) h1[j] = fmaf(xv, sW1[f * FH1 + j], h1[j]);
    }
#pragma unroll
    for (int j = 0; j < FH1; ++j) h1[j] = fmaxf(h1[j], 0.0f);

    float yv[FH2];
#pragma unroll
    for (int j = 0; j < FH2; ++j) yv[j] = 0.0f;
#pragma unroll
    for (int k2 = 0; k2 < FH1; ++k2) {
        float hv = h1[k2];
#pragma unroll
        for (int j = 0; j < FH2; ++j) yv[j] = fmaf(hv, sW2[k2 * FH2 + j], yv[j]);
    }

    size_t yb = (size_t)node * 4;
    float4 o;
    o.x = yv[0] * di; o.y = yv[1] * di; o.z = yv[2] * di; o.w = yv[3] * di;
    y[yb + 0] = o;
    o.x = yv[4] * di; o.y = yv[5] * di; o.z = yv[6] * di; o.w = yv[7] * di;
    y[yb + 1] = o;
    o.x = yv[8] * di; o.y = yv[9] * di; o.z = yv[10] * di; o.w = yv[11] * di;
    y[yb + 2] = o;
    o.x = yv[12] * di; o.y = yv[13] * di; o.z = yv[14] * di; o.w = yv[15] * di;
    y[yb + 3] = o;
}

// ---------------- L2: in-LDS CSR sort -> register segmented reduce -> +b2 -> relu -> Wfc ----------------

__global__ __launch_bounds__(256) void l2_sorted(const unsigned int* __restrict__ recs,
                                                 const int* __restrict__ offs,
                                                 const float4* __restrict__ y,
                                                 const float* __restrict__ dinv,
                                                 const float* __restrict__ b2,
                                                 const float* __restrict__ Wfc,
                                                 const float* __restrict__ bfc,
                                                 float2* __restrict__ out) {
    __shared__ int sl_src[SCAP];
    __shared__ int hist[WB], st[WB], cur[WB];
    __shared__ float acc[WB][17];
    __shared__ float sb2[FH2];
    __shared__ float sWfc[FH2 * NC];
    __shared__ float sbfc[NC];
    int t = threadIdx.x;
    if (t < FH2) sb2[t] = b2[t];
    if (t < FH2 * NC) sWfc[t] = Wfc[t];
    if (t < NC) sbfc[t] = bfc[t];
    if (t < WB) hist[t] = 0;
    __syncthreads();

    int b = blockIdx.x;
    int beg = offs[b * NBLK];
    int end = (b + 1 < NBUCK) ? offs[(b + 1) * NBLK] : NEDGES;

    for (int e = beg + t; e < end; e += 256)
        atomicAdd(&hist[recs[e] >> PSHIFT], 1);
    __syncthreads();

    if (t < WB) cur[t] = hist[t];
    __syncthreads();
    for (int off = 1; off < WB; off <<= 1) {
        int v = 0;
        if (t < WB && t >= off) v = cur[t - off];
        __syncthreads();
        if (t < WB) cur[t] += v;
        __syncthreads();
    }
    if (t < WB) {
        st[t] = cur[t] - hist[t];
        cur[t] = cur[t] - hist[t];
    }
    __syncthreads();

    for (int e = beg + t; e < end; e += 256) {
        unsigned r = recs[e];
        int slot = atomicAdd(&cur[r >> PSHIFT], 1);
        sl_src[slot] = (int)(r & SRCMASK);
    }
    __syncthreads();

    // segmented reduce: 4 lanes per node, 2 rounds of 64 nodes (NO atomics)
    int q = t & 3;
#pragma unroll
    for (int r = 0; r < 2; ++r) {
        int n = (t >> 2) + 64 * r;
        int cnt = hist[n];
        int base = st[n];
        float ax = 0.0f, ay = 0.0f, az = 0.0f, aw = 0.0f;
        int k = 0;
        for (; k + 3 < cnt; k += 4) {
            int s0 = sl_src[base + k];
            int s1 = sl_src[base + k + 1];
            int s2 = sl_src[base + k + 2];
            int s3 = sl_src[base + k + 3];
            float4 v0 = y[(size_t)s0 * 4 + q];
            float4 v1 = y[(size_t)s1 * 4 + q];
            float4 v2 = y[(size_t)s2 * 4 + q];
            float4 v3 = y[(size_t)s3 * 4 + q];
            ax += v0.x + v1.x; ay += v0.y + v1.y;
            az += v0.z + v1.z; aw += v0.w + v1.w;
            ax += v2.x + v3.x; ay += v2.y + v3.y;
            az += v2.z + v3.z; aw += v2.w + v3.w;
        }
        for (; k < cnt; ++k) {
            int s0 = sl_src[base + k];
            float4 v0 = y[(size_t)s0 * 4 + q];
            ax += v0.x; ay += v0.y; az += v0.z; aw += v0.w;
        }
        int kb = q * 4;
        acc[n][kb + 0] = ax; acc[n][kb + 1] = ay;
        acc[n][kb + 2] = az; acc[n][kb + 3] = aw;
    }
    __syncthreads();

    int node = b * WB + t;
    if (t >= WB || node >= NNODES) return;

    float di = dinv[node];
    size_t yb = (size_t)node * 4;
    float4 s0 = y[yb + 0], s1 = y[yb + 1], s2 = y[yb + 2], s3 = y[yb + 3];
    float self[FH2] = {s0.x, s0.y, s0.z, s0.w, s1.x, s1.y, s1.z, s1.w,
                       s2.x, s2.y, s2.z, s2.w, s3.x, s3.y, s3.z, s3.w};

    float o0 = sbfc[0], o1 = sbfc[1];
#pragma unroll
    for (int k = 0; k < FH2; ++k) {
        float h = fmaxf(fmaf(di, acc[t][k] + self[k], sb2[k]), 0.0f);
        o0 = fmaf(h, sWfc[k * NC + 0], o0);
        o1 = fmaf(h, sWfc[k * NC + 1], o1);
    }
    float2 ov; ov.x = o0; ov.y = o1;
    out[node] = ov;
}

// ---------------- launch ----------------

extern "C" void kernel_launch(void* const* d_in, const int* in_sizes, int n_in,
                              void* d_out, int out_size, void* d_ws, size_t ws_size,
                              hipStream_t stream) {
    const float* x   = (const float*)d_in[0];
    const int*   ei  = (const int*)d_in[1];
    const float* W1  = (const float*)d_in[2];
    const float* b1  = (const float*)d_in[3];
    const float* W2  = (const float*)d_in[4];
    const float* b2  = (const float*)d_in[5];
    const float* Wfc = (const float*)d_in[6];
    const float* bfc = (const float*)d_in[7];
    float* out = (float*)d_out;

    char* p = (char*)d_ws;
    auto carve = [&](size_t bytes) -> char* {
        char* r = p;
        p += (bytes + 255) & ~(size_t)255;
        return r;
    };
    int*      counts = (int*)carve((size_t)SCAN_N * 4);
    int*      offs   = (int*)carve((size_t)SCAN_N * 4);
    int*      part   = (int*)carve(128 * 4);
    float*    dinv   = (float*)carve((size_t)NNODES * 4);
    float*    gx     = (float*)carve((size_t)NNODES * 8 * 4);
    float*    y      = (float*)carve((size_t)NNODES * 16 * 4);
    unsigned* recs   = (unsigned*)carve((size_t)NEDGES * 4);
    // total ~48.9 MB (identical to the proven round-0 footprint)

    int nblocks = (NNODES + 255) / 256;

    p1_count<<<NBLK, 256, 0, stream>>>(ei, counts);
    scan_sums<<<SCAN_NT, 256, 0, stream>>>(counts, part);
    scan_top_g<<<1, 64, 0, stream>>>(part);
    scan_write_g<<<SCAN_NT, 256, 0, stream>>>(counts, part, offs);
    p2_scatter<<<NBLK, 256, 0, stream>>>(ei, offs, recs);
    p3_dinv<<<NBUCK, 256, 0, stream>>>(recs, offs, dinv);
    gx_kernel<<<nblocks, 256, 0, stream>>>(x, dinv, (float4*)gx);
    l1_sorted<<<NBUCK, 256, 0, stream>>>(recs, offs, (const float4*)gx, dinv,
                                         W1, b1, W2, (float4*)y);
    l2_sorted<<<NBUCK, 256, 0, stream>>>(recs, offs, (const float4*)y, dinv,
                                         b2, Wfc, bfc, (float2*)out);
}

// Round 6
// 412.211 us; speedup vs baseline: 3.5323x; 1.0167x over previous
//
#include <hip/hip_runtime.h>

#define NNODES 200000
#define NEDGES 6400000
#define FIN 7
#define FH1 32
#define FH2 16
#define NC 2

// bucketing
#define WB 128                       // nodes per bucket
#define WB_SHIFT 7
#define NBUCK ((NNODES + WB - 1) / WB)   // 1563
#define NBLK 512                      // blocks for count/scatter passes (2/CU -> 8 waves/CU)
#define CHUNK ((NEDGES + NBLK - 1) / NBLK)  // 12500
#define PSHIFT 18
#define SRCMASK ((1u << PSHIFT) - 1)

// per-bucket LDS CSR capacity: Poisson(4095) max over 1563 buckets ~ 4400; 16-sigma margin
#define SCAP 5120

// scan over counts[NBUCK][NBLK]
#define SCAN_N (NBUCK * NBLK)        // 800256
#define SCAN_ITEMS 16
#define SCAN_TILE (256 * SCAN_ITEMS) // 4096
#define SCAN_NT ((SCAN_N + SCAN_TILE - 1) / SCAN_TILE)  // 196

// ---------------- P1: per-block bucket histogram ----------------

__global__ __launch_bounds__(256) void p1_count(const int* __restrict__ ei,
                                                int* __restrict__ counts) {
    __shared__ int h[NBUCK];
    for (int i = threadIdx.x; i < NBUCK; i += 256) h[i] = 0;
    __syncthreads();
    int base = blockIdx.x * CHUNK;
    int end = base + CHUNK;
    if (end > NEDGES) end = NEDGES;
    for (int e = base + threadIdx.x; e < end; e += 256) {
        int d = ei[NEDGES + e];
        atomicAdd(&h[d >> WB_SHIFT], 1);
    }
    __syncthreads();
    for (int i = threadIdx.x; i < NBUCK; i += 256)
        counts[i * NBLK + blockIdx.x] = h[i];
}

// ---------------- scan (3 kernels; scan_write_g runs IN-PLACE: out aliases in) ----------------

__global__ __launch_bounds__(256) void scan_sums(const int* __restrict__ in,
                                                 int* __restrict__ part) {
    int base = blockIdx.x * SCAN_TILE + threadIdx.x * SCAN_ITEMS;
    int s = 0;
#pragma unroll
    for (int k = 0; k < SCAN_ITEMS; ++k) {
        int idx = base + k;
        if (idx < SCAN_N) s += in[idx];
    }
    __shared__ int sm[256];
    sm[threadIdx.x] = s;
    __syncthreads();
    for (int off = 128; off > 0; off >>= 1) {
        if (threadIdx.x < off) sm[threadIdx.x] += sm[threadIdx.x + off];
        __syncthreads();
    }
    if (threadIdx.x == 0) part[blockIdx.x] = sm[0];
}

__global__ void scan_top_g(int* __restrict__ part) {
    if (threadIdx.x == 0 && blockIdx.x == 0) {
        int acc = 0;
        for (int i = 0; i < SCAN_NT; ++i) {
            int v = part[i];
            part[i] = acc;
            acc += v;
        }
    }
}

__global__ __launch_bounds__(256) void scan_write_g(const int* __restrict__ in,
                                                    const int* __restrict__ part,
                                                    int* __restrict__ out) {
    int t = threadIdx.x;
    int base = blockIdx.x * SCAN_TILE + t * SCAN_ITEMS;
    int local[SCAN_ITEMS];
    int s = 0;
#pragma unroll
    for (int k = 0; k < SCAN_ITEMS; ++k) {
        int idx = base + k;
        int v = (idx < SCAN_N) ? in[idx] : 0;
        local[k] = v;
        s += v;
    }
    __shared__ int sm[256];
    sm[t] = s;
    __syncthreads();
    for (int off = 1; off < 256; off <<= 1) {
        int v = (t >= off) ? sm[t - off] : 0;
        __syncthreads();
        sm[t] += v;
        __syncthreads();
    }
    int prefix = part[blockIdx.x] + sm[t] - s;  // exclusive
#pragma unroll
    for (int k = 0; k < SCAN_ITEMS; ++k) {
        int idx = base + k;
        if (idx < SCAN_N) {
            out[idx] = prefix;          // in-place safe: local[] already holds inputs
            prefix += local[k];
        }
    }
}

// ---------------- P2: scatter packed records into buckets (coalesced slices) ----------------

__global__ __launch_bounds__(256) void p2_scatter(const int* __restrict__ ei,
                                                  const int* __restrict__ offs,
                                                  unsigned int* __restrict__ recs) {
    __shared__ int cur[NBUCK];
    for (int i = threadIdx.x; i < NBUCK; i += 256)
        cur[i] = offs[i * NBLK + blockIdx.x];
    __syncthreads();
    int base = blockIdx.x * CHUNK;
    int end = base + CHUNK;
    if (end > NEDGES) end = NEDGES;
    for (int e = base + threadIdx.x; e < end; e += 256) {
        int s = ei[e];
        int d = ei[NEDGES + e];
        int b = d >> WB_SHIFT;
        int slot = atomicAdd(&cur[b], 1);
        recs[slot] = (unsigned)s | ((unsigned)(d & (WB - 1)) << PSHIFT);
    }
}

// ---------------- P3: per-bucket degree -> dinv ----------------

__global__ __launch_bounds__(256) void p3_dinv(const unsigned int* __restrict__ recs,
                                               const int* __restrict__ offs,
                                               float* __restrict__ dinv) {
    __shared__ int h[WB];
    int b = blockIdx.x;
    if (threadIdx.x < WB) h[threadIdx.x] = 0;
    __syncthreads();
    int beg = offs[b * NBLK];
    int end = (b + 1 < NBUCK) ? offs[(b + 1) * NBLK] : NEDGES;
    for (int e = beg + threadIdx.x; e < end; e += 256)
        atomicAdd(&h[recs[e] >> PSHIFT], 1);
    __syncthreads();
    int node = b * WB + threadIdx.x;
    if (threadIdx.x < WB && node < NNODES)
        dinv[node] = rsqrtf((float)(1 + h[threadIdx.x]));
}

// ---------------- gx = dinv * x, padded 7 -> 8 (pad lane = 0.0f) ----------------

__global__ __launch_bounds__(256) void gx_kernel(const float* __restrict__ x,
                                                 const float* __restrict__ dinv,
                                                 float4* __restrict__ gx) {
    int i = blockIdx.x * blockDim.x + threadIdx.x;
    if (i >= NNODES) return;
    float di = dinv[i];
    const float* xr = x + (size_t)i * FIN;
    float4 v0, v1;
    v0.x = xr[0] * di; v0.y = xr[1] * di; v0.z = xr[2] * di; v0.w = xr[3] * di;
    v1.x = xr[4] * di; v1.y = xr[5] * di; v1.z = xr[6] * di; v1.w = 0.0f;
    gx[(size_t)i * 2 + 0] = v0;
    gx[(size_t)i * 2 + 1] = v1;
}

// ---------------- L1: in-LDS CSR sort -> register segmented reduce -> W1 -> relu -> W2 ----------------

__global__ __launch_bounds__(256) void l1_sorted(const unsigned int* __restrict__ recs,
                                                 const int* __restrict__ offs,
                                                 const float4* __restrict__ gx,
                                                 const float* __restrict__ dinv,
                                                 const float* __restrict__ W1,
                                                 const float* __restrict__ b1,
                                                 const float* __restrict__ W2,
                                                 float4* __restrict__ y) {
    __shared__ int sl_src[SCAP];
    __shared__ int hist[WB], st[WB], cur[WB];
    __shared__ float acc[WB][9];
    __shared__ float sW1[FIN * FH1];
    __shared__ float sb1[FH1];
    __shared__ float sW2[FH1 * FH2];
    int t = threadIdx.x;
    for (int i = t; i < FIN * FH1; i += 256) sW1[i] = W1[i];
    if (t < FH1) sb1[t] = b1[t];
    for (int i = t; i < FH1 * FH2; i += 256) sW2[i] = W2[i];
    if (t < WB) hist[t] = 0;
    __syncthreads();

    int b = blockIdx.x;
    int beg = offs[b * NBLK];
    int end = (b + 1 < NBUCK) ? offs[(b + 1) * NBLK] : NEDGES;

    // pass A: local-destination histogram
    for (int e = beg + t; e < end; e += 256)
        atomicAdd(&hist[recs[e] >> PSHIFT], 1);
    __syncthreads();

    // exclusive scan of hist[128] (Hillis-Steele, uniform barriers)
    if (t < WB) cur[t] = hist[t];
    __syncthreads();
    for (int off = 1; off < WB; off <<= 1) {
        int v = 0;
        if (t < WB && t >= off) v = cur[t - off];
        __syncthreads();
        if (t < WB) cur[t] += v;
        __syncthreads();
    }
    if (t < WB) {
        st[t] = cur[t] - hist[t];
        cur[t] = cur[t] - hist[t];
    }
    __syncthreads();

    // pass B: scatter src into LDS CSR (records L2-warm from pass A)
    for (int e = beg + t; e < end; e += 256) {
        unsigned r = recs[e];
        int slot = atomicAdd(&cur[r >> PSHIFT], 1);
        sl_src[slot] = (int)(r & SRCMASK);
    }
    __syncthreads();

    // segmented reduce: 2 lanes per node, accumulate in registers (NO atomics)
    int n = t >> 1;
    int hq = t & 1;
    int cnt = hist[n];
    int base = st[n];
    float ax = 0.0f, ay = 0.0f, az = 0.0f, aw = 0.0f;
    int k = 0;
    for (; k + 3 < cnt; k += 4) {
        int s0 = sl_src[base + k];
        int s1 = sl_src[base + k + 1];
        int s2 = sl_src[base + k + 2];
        int s3 = sl_src[base + k + 3];
        float4 v0 = gx[(size_t)s0 * 2 + hq];
        float4 v1 = gx[(size_t)s1 * 2 + hq];
        float4 v2 = gx[(size_t)s2 * 2 + hq];
        float4 v3 = gx[(size_t)s3 * 2 + hq];
        ax += v0.x + v1.x; ay += v0.y + v1.y;
        az += v0.z + v1.z; aw += v0.w + v1.w;
        ax += v2.x + v3.x; ay += v2.y + v3.y;
        az += v2.z + v3.z; aw += v2.w + v3.w;
    }
    for (; k < cnt; ++k) {
        int s0 = sl_src[base + k];
        float4 v0 = gx[(size_t)s0 * 2 + hq];
        ax += v0.x; ay += v0.y; az += v0.z; aw += v0.w;
    }
    int kb = hq * 4;
    acc[n][kb + 0] = ax; acc[n][kb + 1] = ay;
    acc[n][kb + 2] = az; acc[n][kb + 3] = aw;
    __syncthreads();

    int node = b * WB + t;
    if (t >= WB || node >= NNODES) return;

    float di = dinv[node];
    float4 g0 = gx[(size_t)node * 2], g1 = gx[(size_t)node * 2 + 1];
    float xa[FIN];
    xa[0] = (acc[t][0] + g0.x) * di;
    xa[1] = (acc[t][1] + g0.y) * di;
    xa[2] = (acc[t][2] + g0.z) * di;
    xa[3] = (acc[t][3] + g0.w) * di;
    xa[4] = (acc[t][4] + g1.x) * di;
    xa[5] = (acc[t][5] + g1.y) * di;
    xa[6] = (acc[t][6] + g1.z) * di;

    float h1[FH1];
#pragma unroll
    for (int j = 0; j < FH1; ++j) h1[j] = sb1[j];
#pragma unroll
    for (int f = 0; f < FIN; ++f) {
        float xv = xa[f];
#pragma unroll
        for (int j = 0; j < FH1; ++j) h1[j] = fmaf(xv, sW1[f * FH1 + j], h1[j]);
    }
#pragma unroll
    for (int j = 0; j < FH1; ++j) h1[j] = fmaxf(h1[j], 0.0f);

    float yv[FH2];
#pragma unroll
    for (int j = 0; j < FH2; ++j) yv[j] = 0.0f;
#pragma unroll
    for (int k2 = 0; k2 < FH1; ++k2) {
        float hv = h1[k2];
#pragma unroll
        for (int j = 0; j < FH2; ++j) yv[j] = fmaf(hv, sW2[k2 * FH2 + j], yv[j]);
    }

    size_t yb = (size_t)node * 4;
    float4 o;
    o.x = yv[0] * di; o.y = yv[1] * di; o.z = yv[2] * di; o.w = yv[3] * di;
    y[yb + 0] = o;
    o.x = yv[4] * di; o.y = yv[5] * di; o.z = yv[6] * di; o.w = yv[7] * di;
    y[yb + 1] = o;
    o.x = yv[8] * di; o.y = yv[9] * di; o.z = yv[10] * di; o.w = yv[11] * di;
    y[yb + 2] = o;
    o.x = yv[12] * di; o.y = yv[13] * di; o.z = yv[14] * di; o.w = yv[15] * di;
    y[yb + 3] = o;
}

// ---------------- L2: in-LDS CSR sort -> register segmented reduce -> +b2 -> relu -> Wfc ----------------

__global__ __launch_bounds__(256) void l2_sorted(const unsigned int* __restrict__ recs,
                                                 const int* __restrict__ offs,
                                                 const float4* __restrict__ y,
                                                 const float* __restrict__ dinv,
                                                 const float* __restrict__ b2,
                                                 const float* __restrict__ Wfc,
                                                 const float* __restrict__ bfc,
                                                 float2* __restrict__ out) {
    __shared__ int sl_src[SCAP];
    __shared__ int hist[WB], st[WB], cur[WB];
    __shared__ float acc[WB][17];
    __shared__ float sb2[FH2];
    __shared__ float sWfc[FH2 * NC];
    __shared__ float sbfc[NC];
    int t = threadIdx.x;
    if (t < FH2) sb2[t] = b2[t];
    if (t < FH2 * NC) sWfc[t] = Wfc[t];
    if (t < NC) sbfc[t] = bfc[t];
    if (t < WB) hist[t] = 0;
    __syncthreads();

    int b = blockIdx.x;
    int beg = offs[b * NBLK];
    int end = (b + 1 < NBUCK) ? offs[(b + 1) * NBLK] : NEDGES;

    for (int e = beg + t; e < end; e += 256)
        atomicAdd(&hist[recs[e] >> PSHIFT], 1);
    __syncthreads();

    if (t < WB) cur[t] = hist[t];
    __syncthreads();
    for (int off = 1; off < WB; off <<= 1) {
        int v = 0;
        if (t < WB && t >= off) v = cur[t - off];
        __syncthreads();
        if (t < WB) cur[t] += v;
        __syncthreads();
    }
    if (t < WB) {
        st[t] = cur[t] - hist[t];
        cur[t] = cur[t] - hist[t];
    }
    __syncthreads();

    for (int e = beg + t; e < end; e += 256) {
        unsigned r = recs[e];
        int slot = atomicAdd(&cur[r >> PSHIFT], 1);
        sl_src[slot] = (int)(r & SRCMASK);
    }
    __syncthreads();

    // segmented reduce: 4 lanes per node, 2 rounds of 64 nodes (NO atomics)
    int q = t & 3;
#pragma unroll
    for (int r = 0; r < 2; ++r) {
        int n = (t >> 2) + 64 * r;
        int cnt = hist[n];
        int base = st[n];
        float ax = 0.0f, ay = 0.0f, az = 0.0f, aw = 0.0f;
        int k = 0;
        for (; k + 3 < cnt; k += 4) {
            int s0 = sl_src[base + k];
            int s1 = sl_src[base + k + 1];
            int s2 = sl_src[base + k + 2];
            int s3 = sl_src[base + k + 3];
            float4 v0 = y[(size_t)s0 * 4 + q];
            float4 v1 = y[(size_t)s1 * 4 + q];
            float4 v2 = y[(size_t)s2 * 4 + q];
            float4 v3 = y[(size_t)s3 * 4 + q];
            ax += v0.x + v1.x; ay += v0.y + v1.y;
            az += v0.z + v1.z; aw += v0.w + v1.w;
            ax += v2.x + v3.x; ay += v2.y + v3.y;
            az += v2.z + v3.z; aw += v2.w + v3.w;
        }
        for (; k < cnt; ++k) {
            int s0 = sl_src[base + k];
            float4 v0 = y[(size_t)s0 * 4 + q];
            ax += v0.x; ay += v0.y; az += v0.z; aw += v0.w;
        }
        int kb = q * 4;
        acc[n][kb + 0] = ax; acc[n][kb + 1] = ay;
        acc[n][kb + 2] = az; acc[n][kb + 3] = aw;
    }
    __syncthreads();

    int node = b * WB + t;
    if (t >= WB || node >= NNODES) return;

    float di = dinv[node];
    size_t yb = (size_t)node * 4;
    float4 s0 = y[yb + 0], s1 = y[yb + 1], s2 = y[yb + 2], s3 = y[yb + 3];
    float self[FH2] = {s0.x, s0.y, s0.z, s0.w, s1.x, s1.y, s1.z, s1.w,
                       s2.x, s2.y, s2.z, s2.w, s3.x, s3.y, s3.z, s3.w};

    float o0 = sbfc[0], o1 = sbfc[1];
#pragma unroll
    for (int k = 0; k < FH2; ++k) {
        float h = fmaxf(fmaf(di, acc[t][k] + self[k], sb2[k]), 0.0f);
        o0 = fmaf(h, sWfc[k * NC + 0], o0);
        o1 = fmaf(h, sWfc[k * NC + 1], o1);
    }
    float2 ov; ov.x = o0; ov.y = o1;
    out[node] = ov;
}

// ---------------- launch ----------------

extern "C" void kernel_launch(void* const* d_in, const int* in_sizes, int n_in,
                              void* d_out, int out_size, void* d_ws, size_t ws_size,
                              hipStream_t stream) {
    const float* x   = (const float*)d_in[0];
    const int*   ei  = (const int*)d_in[1];
    const float* W1  = (const float*)d_in[2];
    const float* b1  = (const float*)d_in[3];
    const float* W2  = (const float*)d_in[4];
    const float* b2  = (const float*)d_in[5];
    const float* Wfc = (const float*)d_in[6];
    const float* bfc = (const float*)d_in[7];
    float* out = (float*)d_out;

    char* p = (char*)d_ws;
    auto carve = [&](size_t bytes) -> char* {
        char* r = p;
        p += (bytes + 255) & ~(size_t)255;
        return r;
    };
    int*      counts = (int*)carve((size_t)SCAN_N * 4);   // scanned IN-PLACE -> becomes offs
    int*      part   = (int*)carve(256 * 4);
    float*    dinv   = (float*)carve((size_t)NNODES * 4);
    float*    gx     = (float*)carve((size_t)NNODES * 8 * 4);
    float*    y      = (float*)carve((size_t)NNODES * 16 * 4);
    unsigned* recs   = (unsigned*)carve((size_t)NEDGES * 4);
    // total ~48.9 MB (same as the proven round-0 footprint: counts doubled, offs eliminated)
    int* offs = counts;  // alias: scan_write_g rewrites counts into exclusive offsets

    int nblocks = (NNODES + 255) / 256;

    p1_count<<<NBLK, 256, 0, stream>>>(ei, counts);
    scan_sums<<<SCAN_NT, 256, 0, stream>>>(counts, part);
    scan_top_g<<<1, 64, 0, stream>>>(part);
    scan_write_g<<<SCAN_NT, 256, 0, stream>>>(counts, part, offs);  // in-place
    p2_scatter<<<NBLK, 256, 0, stream>>>(ei, offs, recs);
    p3_dinv<<<NBUCK, 256, 0, stream>>>(recs, offs, dinv);
    gx_kernel<<<nblocks, 256, 0, stream>>>(x, dinv, (float4*)gx);
    l1_sorted<<<NBUCK, 256, 0, stream>>>(recs, offs, (const float4*)gx, dinv,
                                         W1, b1, W2, (float4*)y);
    l2_sorted<<<NBUCK, 256, 0, stream>>>(recs, offs, (const float4*)y, dinv,
                                         b2, Wfc, bfc, (float2*)out);
}

// Round 7
// 382.107 us; speedup vs baseline: 3.8106x; 1.0788x over previous
//
#include <hip/hip_runtime.h>

#define NNODES 200000
#define NEDGES 6400000
#define FIN 7
#define FH1 32
#define FH2 16
#define NC 2

// bucketing
#define WB 128                       // nodes per bucket
#define WB_SHIFT 7
#define NBUCK ((NNODES + WB - 1) / WB)   // 1563
#define NBLK 512                      // blocks for count/scatter passes (2/CU)
#define CHUNK ((NEDGES + NBLK - 1) / NBLK)  // 12500 (exact: 512*12500 = 6.4M)
#define PSHIFT 18
#define SRCMASK ((1u << PSHIFT) - 1)

// per-bucket LDS CSR capacity: Poisson(4095) max over 1563 buckets ~ 4400; 16-sigma margin
#define SCAP 5120

// scan over counts[NBUCK][NBLK]
#define SCAN_N (NBUCK * NBLK)        // 800256
#define SCAN_ITEMS 16
#define SCAN_TILE (256 * SCAN_ITEMS) // 4096
#define SCAN_NT ((SCAN_N + SCAN_TILE - 1) / SCAN_TILE)  // 196

// ---------------- P1: per-block bucket histogram ----------------

__global__ __launch_bounds__(256) void p1_count(const int* __restrict__ ei,
                                                int* __restrict__ counts) {
    __shared__ int h[NBUCK];
    for (int i = threadIdx.x; i < NBUCK; i += 256) h[i] = 0;
    __syncthreads();
    int base = blockIdx.x * CHUNK;
    int end = base + CHUNK;
    if (end > NEDGES) end = NEDGES;
    for (int e = base + threadIdx.x; e < end; e += 256) {
        int d = ei[NEDGES + e];
        atomicAdd(&h[d >> WB_SHIFT], 1);
    }
    __syncthreads();
    for (int i = threadIdx.x; i < NBUCK; i += 256)
        counts[i * NBLK + blockIdx.x] = h[i];
}

// ---------------- scan (3 kernels; scan_write_g runs IN-PLACE: out aliases in) ----------------

__global__ __launch_bounds__(256) void scan_sums(const int* __restrict__ in,
                                                 int* __restrict__ part) {
    int base = blockIdx.x * SCAN_TILE + threadIdx.x * SCAN_ITEMS;
    int s = 0;
#pragma unroll
    for (int k = 0; k < SCAN_ITEMS; ++k) {
        int idx = base + k;
        if (idx < SCAN_N) s += in[idx];
    }
    __shared__ int sm[256];
    sm[threadIdx.x] = s;
    __syncthreads();
    for (int off = 128; off > 0; off >>= 1) {
        if (threadIdx.x < off) sm[threadIdx.x] += sm[threadIdx.x + off];
        __syncthreads();
    }
    if (threadIdx.x == 0) part[blockIdx.x] = sm[0];
}

__global__ void scan_top_g(int* __restrict__ part) {
    if (threadIdx.x == 0 && blockIdx.x == 0) {
        int acc = 0;
        for (int i = 0; i < SCAN_NT; ++i) {
            int v = part[i];
            part[i] = acc;
            acc += v;
        }
    }
}

__global__ __launch_bounds__(256) void scan_write_g(const int* __restrict__ in,
                                                    const int* __restrict__ part,
                                                    int* __restrict__ out) {
    int t = threadIdx.x;
    int base = blockIdx.x * SCAN_TILE + t * SCAN_ITEMS;
    int local[SCAN_ITEMS];
    int s = 0;
#pragma unroll
    for (int k = 0; k < SCAN_ITEMS; ++k) {
        int idx = base + k;
        int v = (idx < SCAN_N) ? in[idx] : 0;
        local[k] = v;
        s += v;
    }
    __shared__ int sm[256];
    sm[t] = s;
    __syncthreads();
    for (int off = 1; off < 256; off <<= 1) {
        int v = (t >= off) ? sm[t - off] : 0;
        __syncthreads();
        sm[t] += v;
        __syncthreads();
    }
    int prefix = part[blockIdx.x] + sm[t] - s;  // exclusive
#pragma unroll
    for (int k = 0; k < SCAN_ITEMS; ++k) {
        int idx = base + k;
        if (idx < SCAN_N) {
            out[idx] = prefix;          // in-place safe: local[] already holds inputs
            prefix += local[k];
        }
    }
}

// ---------------- P2: LDS-sorted scatter -> coalesced slice bursts ----------------
// Each block sorts its 12500-edge chunk by bucket in LDS, then flushes each
// bucket's run (~8 recs) with consecutive threads -> consecutive global
// addresses. Scattered 4B lane-writes (6.4M) become ~8-record coalesced
// bursts (~0.8M line requests): attacks the measured issue-bound limit.

__global__ __launch_bounds__(256) void p2_scatter(const int* __restrict__ ei,
                                                  const int* __restrict__ offs,
                                                  unsigned int* __restrict__ recs) {
    __shared__ int sorted[CHUNK];    // 50000 B
    __shared__ int lcur[NBUCK];      // 6252 B: sizes -> starts -> cursors -> inclusive ends
    __shared__ int gbase[NBUCK];     // 6252 B: global slice base per bucket
    __shared__ int sm[256];          // 1024 B scan temp   (total 63528 B < 64K)
    int t = threadIdx.x;
    int blk = blockIdx.x;

    // 1. load slice bases + local counts (offs column diffs)
    for (int b = t; b < NBUCK; b += 256) {
        int g = offs[b * NBLK + blk];
        gbase[b] = g;
        int nxt;
        if (blk + 1 < NBLK) nxt = offs[b * NBLK + blk + 1];
        else nxt = (b + 1 < NBUCK) ? offs[(b + 1) * NBLK] : NEDGES;
        lcur[b] = nxt - g;
    }
    __syncthreads();

    // 2. exclusive scan of local counts -> run starts (7 items/thread covers 1792 >= 1563)
    int base7 = t * 7;
    int loc[7];
    int s = 0;
#pragma unroll
    for (int k = 0; k < 7; ++k) {
        int idx = base7 + k;
        int v = (idx < NBUCK) ? lcur[idx] : 0;
        loc[k] = v;
        s += v;
    }
    sm[t] = s;
    __syncthreads();
    for (int off = 1; off < 256; off <<= 1) {
        int v = (t >= off) ? sm[t - off] : 0;
        __syncthreads();
        sm[t] += v;
        __syncthreads();
    }
    int run = sm[t] - s;  // exclusive prefix of this thread's group
#pragma unroll
    for (int k = 0; k < 7; ++k) {
        int idx = base7 + k;
        if (idx < NBUCK) { lcur[idx] = run; run += loc[k]; }  // exclusive starts
    }
    __syncthreads();

    // 3. scatter chunk into LDS at local cursor positions
    int ebase = blk * CHUNK;
    for (int e = ebase + t; e < ebase + CHUNK; e += 256) {
        int src = ei[e];
        int d = ei[NEDGES + e];
        int b = d >> WB_SHIFT;
        int slot = atomicAdd(&lcur[b], 1);
        sorted[slot] = (int)((unsigned)src | ((unsigned)(d & (WB - 1)) << PSHIFT));
    }
    __syncthreads();
    // lcur[b] is now the INCLUSIVE end of run b (monotone non-decreasing)

    // 4. coalesced flush: find bucket by binary search, write run-relative
    for (int i = t; i < CHUNK; i += 256) {
        int lo = 0, hi = NBUCK - 1;
        while (lo < hi) {
            int mid = (lo + hi) >> 1;
            if (lcur[mid] > i) hi = mid; else lo = mid + 1;
        }
        int b = lo;
        int start = (b > 0) ? lcur[b - 1] : 0;
        recs[gbase[b] + (i - start)] = (unsigned)sorted[i];
    }
}

// ---------------- P3: per-bucket degree -> dinv ----------------

__global__ __launch_bounds__(256) void p3_dinv(const unsigned int* __restrict__ recs,
                                               const int* __restrict__ offs,
                                               float* __restrict__ dinv) {
    __shared__ int h[WB];
    int b = blockIdx.x;
    if (threadIdx.x < WB) h[threadIdx.x] = 0;
    __syncthreads();
    int beg = offs[b * NBLK];
    int end = (b + 1 < NBUCK) ? offs[(b + 1) * NBLK] : NEDGES;
    for (int e = beg + threadIdx.x; e < end; e += 256)
        atomicAdd(&h[recs[e] >> PSHIFT], 1);
    __syncthreads();
    int node = b * WB + threadIdx.x;
    if (threadIdx.x < WB && node < NNODES)
        dinv[node] = rsqrtf((float)(1 + h[threadIdx.x]));
}

// ---------------- gx = dinv * x, padded 7 -> 8 (pad lane = 0.0f) ----------------

__global__ __launch_bounds__(256) void gx_kernel(const float* __restrict__ x,
                                                 const float* __restrict__ dinv,
                                                 float4* __restrict__ gx) {
    int i = blockIdx.x * blockDim.x + threadIdx.x;
    if (i >= NNODES) return;
    float di = dinv[i];
    const float* xr = x + (size_t)i * FIN;
    float4 v0, v1;
    v0.x = xr[0] * di; v0.y = xr[1] * di; v0.z = xr[2] * di; v0.w = xr[3] * di;
    v1.x = xr[4] * di; v1.y = xr[5] * di; v1.z = xr[6] * di; v1.w = 0.0f;
    gx[(size_t)i * 2 + 0] = v0;
    gx[(size_t)i * 2 + 1] = v1;
}

// ---------------- L1: in-LDS CSR sort -> register segmented reduce -> W1 -> relu -> W2 ----------------

__global__ __launch_bounds__(256) void l1_sorted(const unsigned int* __restrict__ recs,
                                                 const int* __restrict__ offs,
                                                 const float4* __restrict__ gx,
                                                 const float* __restrict__ dinv,
                                                 const float* __restrict__ W1,
                                                 const float* __restrict__ b1,
                                                 const float* __restrict__ W2,
                                                 float4* __restrict__ y) {
    __shared__ int sl_src[SCAP];
    __shared__ int hist[WB], st[WB], cur[WB];
    __shared__ float acc[WB][9];
    __shared__ float sW1[FIN * FH1];
    __shared__ float sb1[FH1];
    __shared__ float sW2[FH1 * FH2];
    int t = threadIdx.x;
    for (int i = t; i < FIN * FH1; i += 256) sW1[i] = W1[i];
    if (t < FH1) sb1[t] = b1[t];
    for (int i = t; i < FH1 * FH2; i += 256) sW2[i] = W2[i];
    if (t < WB) hist[t] = 0;
    __syncthreads();

    int b = blockIdx.x;
    int beg = offs[b * NBLK];
    int end = (b + 1 < NBUCK) ? offs[(b + 1) * NBLK] : NEDGES;

    // pass A: local-destination histogram
    for (int e = beg + t; e < end; e += 256)
        atomicAdd(&hist[recs[e] >> PSHIFT], 1);
    __syncthreads();

    // exclusive scan of hist[128] (Hillis-Steele, uniform barriers)
    if (t < WB) cur[t] = hist[t];
    __syncthreads();
    for (int off = 1; off < WB; off <<= 1) {
        int v = 0;
        if (t < WB && t >= off) v = cur[t - off];
        __syncthreads();
        if (t < WB) cur[t] += v;
        __syncthreads();
    }
    if (t < WB) {
        st[t] = cur[t] - hist[t];
        cur[t] = cur[t] - hist[t];
    }
    __syncthreads();

    // pass B: scatter src into LDS CSR (records L2-warm from pass A)
    for (int e = beg + t; e < end; e += 256) {
        unsigned r = recs[e];
        int slot = atomicAdd(&cur[r >> PSHIFT], 1);
        sl_src[slot] = (int)(r & SRCMASK);
    }
    __syncthreads();

    // segmented reduce: 2 lanes per node, accumulate in registers (NO atomics)
    int n = t >> 1;
    int hq = t & 1;
    int cnt = hist[n];
    int base = st[n];
    float ax = 0.0f, ay = 0.0f, az = 0.0f, aw = 0.0f;
    int k = 0;
    for (; k + 3 < cnt; k += 4) {
        int s0 = sl_src[base + k];
        int s1 = sl_src[base + k + 1];
        int s2 = sl_src[base + k + 2];
        int s3 = sl_src[base + k + 3];
        float4 v0 = gx[(size_t)s0 * 2 + hq];
        float4 v1 = gx[(size_t)s1 * 2 + hq];
        float4 v2 = gx[(size_t)s2 * 2 + hq];
        float4 v3 = gx[(size_t)s3 * 2 + hq];
        ax += v0.x + v1.x; ay += v0.y + v1.y;
        az += v0.z + v1.z; aw += v0.w + v1.w;
        ax += v2.x + v3.x; ay += v2.y + v3.y;
        az += v2.z + v3.z; aw += v2.w + v3.w;
    }
    for (; k < cnt; ++k) {
        int s0 = sl_src[base + k];
        float4 v0 = gx[(size_t)s0 * 2 + hq];
        ax += v0.x; ay += v0.y; az += v0.z; aw += v0.w;
    }
    int kb = hq * 4;
    acc[n][kb + 0] = ax; acc[n][kb + 1] = ay;
    acc[n][kb + 2] = az; acc[n][kb + 3] = aw;
    __syncthreads();

    int node = b * WB + t;
    if (t >= WB || node >= NNODES) return;

    float di = dinv[node];
    float4 g0 = gx[(size_t)node * 2], g1 = gx[(size_t)node * 2 + 1];
    float xa[FIN];
    xa[0] = (acc[t][0] + g0.x) * di;
    xa[1] = (acc[t][1] + g0.y) * di;
    xa[2] = (acc[t][2] + g0.z) * di;
    xa[3] = (acc[t][3] + g0.w) * di;
    xa[4] = (acc[t][4] + g1.x) * di;
    xa[5] = (acc[t][5] + g1.y) * di;
    xa[6] = (acc[t][6] + g1.z) * di;

    float h1[FH1];
#pragma unroll
    for (int j = 0; j < FH1; ++j) h1[j] = sb1[j];
#pragma unroll
    for (int f = 0; f < FIN; ++f) {
        float xv = xa[f];
#pragma unroll
        for (int j = 0; j < FH1; ++j) h1[j] = fmaf(xv, sW1[f * FH1 + j], h1[j]);
    }
#pragma unroll
    for (int j = 0; j < FH1; ++j) h1[j] = fmaxf(h1[j], 0.0f);

    float yv[FH2];
#pragma unroll
    for (int j = 0; j < FH2; ++j) yv[j] = 0.0f;
#pragma unroll
    for (int k2 = 0; k2 < FH1; ++k2) {
        float hv = h1[k2];
#pragma unroll
        for (int j = 0; j < FH2; ++j) yv[j] = fmaf(hv, sW2[k2 * FH2 + j], yv[j]);
    }

    size_t yb = (size_t)node * 4;
    float4 o;
    o.x = yv[0] * di; o.y = yv[1] * di; o.z = yv[2] * di; o.w = yv[3] * di;
    y[yb + 0] = o;
    o.x = yv[4] * di; o.y = yv[5] * di; o.z = yv[6] * di; o.w = yv[7] * di;
    y[yb + 1] = o;
    o.x = yv[8] * di; o.y = yv[9] * di; o.z = yv[10] * di; o.w = yv[11] * di;
    y[yb + 2] = o;
    o.x = yv[12] * di; o.y = yv[13] * di; o.z = yv[14] * di; o.w = yv[15] * di;
    y[yb + 3] = o;
}

// ---------------- L2: in-LDS CSR sort -> register segmented reduce -> +b2 -> relu -> Wfc ----------------

__global__ __launch_bounds__(256) void l2_sorted(const unsigned int* __restrict__ recs,
                                                 const int* __restrict__ offs,
                                                 const float4* __restrict__ y,
                                                 const float* __restrict__ dinv,
                                                 const float* __restrict__ b2,
                                                 const float* __restrict__ Wfc,
                                                 const float* __restrict__ bfc,
                                                 float2* __restrict__ out) {
    __shared__ int sl_src[SCAP];
    __shared__ int hist[WB], st[WB], cur[WB];
    __shared__ float acc[WB][17];
    __shared__ float sb2[FH2];
    __shared__ float sWfc[FH2 * NC];
    __shared__ float sbfc[NC];
    int t = threadIdx.x;
    if (t < FH2) sb2[t] = b2[t];
    if (t < FH2 * NC) sWfc[t] = Wfc[t];
    if (t < NC) sbfc[t] = bfc[t];
    if (t < WB) hist[t] = 0;
    __syncthreads();

    int b = blockIdx.x;
    int beg = offs[b * NBLK];
    int end = (b + 1 < NBUCK) ? offs[(b + 1) * NBLK] : NEDGES;

    for (int e = beg + t; e < end; e += 256)
        atomicAdd(&hist[recs[e] >> PSHIFT], 1);
    __syncthreads();

    if (t < WB) cur[t] = hist[t];
    __syncthreads();
    for (int off = 1; off < WB; off <<= 1) {
        int v = 0;
        if (t < WB && t >= off) v = cur[t - off];
        __syncthreads();
        if (t < WB) cur[t] += v;
        __syncthreads();
    }
    if (t < WB) {
        st[t] = cur[t] - hist[t];
        cur[t] = cur[t] - hist[t];
    }
    __syncthreads();

    for (int e = beg + t; e < end; e += 256) {
        unsigned r = recs[e];
        int slot = atomicAdd(&cur[r >> PSHIFT], 1);
        sl_src[slot] = (int)(r & SRCMASK);
    }
    __syncthreads();

    // segmented reduce: 4 lanes per node, 2 rounds of 64 nodes (NO atomics)
    int q = t & 3;
#pragma unroll
    for (int r = 0; r < 2; ++r) {
        int n = (t >> 2) + 64 * r;
        int cnt = hist[n];
        int base = st[n];
        float ax = 0.0f, ay = 0.0f, az = 0.0f, aw = 0.0f;
        int k = 0;
        for (; k + 3 < cnt; k += 4) {
            int s0 = sl_src[base + k];
            int s1 = sl_src[base + k + 1];
            int s2 = sl_src[base + k + 2];
            int s3 = sl_src[base + k + 3];
            float4 v0 = y[(size_t)s0 * 4 + q];
            float4 v1 = y[(size_t)s1 * 4 + q];
            float4 v2 = y[(size_t)s2 * 4 + q];
            float4 v3 = y[(size_t)s3 * 4 + q];
            ax += v0.x + v1.x; ay += v0.y + v1.y;
            az += v0.z + v1.z; aw += v0.w + v1.w;
            ax += v2.x + v3.x; ay += v2.y + v3.y;
            az += v2.z + v3.z; aw += v2.w + v3.w;
        }
        for (; k < cnt; ++k) {
            int s0 = sl_src[base + k];
            float4 v0 = y[(size_t)s0 * 4 + q];
            ax += v0.x; ay += v0.y; az += v0.z; aw += v0.w;
        }
        int kb = q * 4;
        acc[n][kb + 0] = ax; acc[n][kb + 1] = ay;
        acc[n][kb + 2] = az; acc[n][kb + 3] = aw;
    }
    __syncthreads();

    int node = b * WB + t;
    if (t >= WB || node >= NNODES) return;

    float di = dinv[node];
    size_t yb = (size_t)node * 4;
    float4 s0 = y[yb + 0], s1 = y[yb + 1], s2 = y[yb + 2], s3 = y[yb + 3];
    float self[FH2] = {s0.x, s0.y, s0.z, s0.w, s1.x, s1.y, s1.z, s1.w,
                       s2.x, s2.y, s2.z, s2.w, s3.x, s3.y, s3.z, s3.w};

    float o0 = sbfc[0], o1 = sbfc[1];
#pragma unroll
    for (int k = 0; k < FH2; ++k) {
        float h = fmaxf(fmaf(di, acc[t][k] + self[k], sb2[k]), 0.0f);
        o0 = fmaf(h, sWfc[k * NC + 0], o0);
        o1 = fmaf(h, sWfc[k * NC + 1], o1);
    }
    float2 ov; ov.x = o0; ov.y = o1;
    out[node] = ov;
}

// ---------------- launch ----------------

extern "C" void kernel_launch(void* const* d_in, const int* in_sizes, int n_in,
                              void* d_out, int out_size, void* d_ws, size_t ws_size,
                              hipStream_t stream) {
    const float* x   = (const float*)d_in[0];
    const int*   ei  = (const int*)d_in[1];
    const float* W1  = (const float*)d_in[2];
    const float* b1  = (const float*)d_in[3];
    const float* W2  = (const float*)d_in[4];
    const float* b2  = (const float*)d_in[5];
    const float* Wfc = (const float*)d_in[6];
    const float* bfc = (const float*)d_in[7];
    float* out = (float*)d_out;

    char* p = (char*)d_ws;
    auto carve = [&](size_t bytes) -> char* {
        char* r = p;
        p += (bytes + 255) & ~(size_t)255;
        return r;
    };
    int*      counts = (int*)carve((size_t)SCAN_N * 4);   // scanned IN-PLACE -> becomes offs
    int*      part   = (int*)carve(256 * 4);
    float*    dinv   = (float*)carve((size_t)NNODES * 4);
    float*    gx     = (float*)carve((size_t)NNODES * 8 * 4);
    float*    y      = (float*)carve((size_t)NNODES * 16 * 4);
    unsigned* recs   = (unsigned*)carve((size_t)NEDGES * 4);
    // total ~48.9 MB (same as the proven round-0 footprint)
    int* offs = counts;  // alias: scan_write_g rewrites counts into exclusive offsets

    int nblocks = (NNODES + 255) / 256;

    p1_count<<<NBLK, 256, 0, stream>>>(ei, counts);
    scan_sums<<<SCAN_NT, 256, 0, stream>>>(counts, part);
    scan_top_g<<<1, 64, 0, stream>>>(part);
    scan_write_g<<<SCAN_NT, 256, 0, stream>>>(counts, part, offs);  // in-place
    p2_scatter<<<NBLK, 256, 0, stream>>>(ei, offs, recs);
    p3_dinv<<<NBUCK, 256, 0, stream>>>(recs, offs, dinv);
    gx_kernel<<<nblocks, 256, 0, stream>>>(x, dinv, (float4*)gx);
    l1_sorted<<<NBUCK, 256, 0, stream>>>(recs, offs, (const float4*)gx, dinv,
                                         W1, b1, W2, (float4*)y);
    l2_sorted<<<NBUCK, 256, 0, stream>>>(recs, offs, (const float4*)y, dinv,
                                         b2, Wfc, bfc, (float2*)out);
}

// Round 8
// 375.372 us; speedup vs baseline: 3.8790x; 1.0179x over previous
//
#include <hip/hip_runtime.h>

#define NNODES 200000
#define NEDGES 6400000
#define FIN 7
#define FH1 32
#define FH2 16
#define NC 2

// bucketing
#define WB 128                       // nodes per bucket
#define WB_SHIFT 7
#define NBUCK ((NNODES + WB - 1) / WB)   // 1563
#define NBLK 512                      // blocks for count/scatter passes (2/CU)
#define CHUNK ((NEDGES + NBLK - 1) / NBLK)  // 12500 (exact: 512*12500 = 6.4M)
#define PSHIFT 18
#define SRCMASK ((1u << PSHIFT) - 1)

// per-bucket LDS capacity: Poisson(4095) max over 1563 buckets ~ 4400; 16-sigma margin
#define SCAP 5120

// scan over counts[NBUCK][NBLK]
#define SCAN_N (NBUCK * NBLK)        // 800256
#define SCAN_ITEMS 16
#define SCAN_TILE (256 * SCAN_ITEMS) // 4096
#define SCAN_NT ((SCAN_N + SCAN_TILE - 1) / SCAN_TILE)  // 196

// ---------------- P1: per-block bucket histogram ----------------

__global__ __launch_bounds__(256) void p1_count(const int* __restrict__ ei,
                                                int* __restrict__ counts) {
    __shared__ int h[NBUCK];
    for (int i = threadIdx.x; i < NBUCK; i += 256) h[i] = 0;
    __syncthreads();
    int base = blockIdx.x * CHUNK;
    int end = base + CHUNK;
    if (end > NEDGES) end = NEDGES;
    for (int e = base + threadIdx.x; e < end; e += 256) {
        int d = ei[NEDGES + e];
        atomicAdd(&h[d >> WB_SHIFT], 1);
    }
    __syncthreads();
    for (int i = threadIdx.x; i < NBUCK; i += 256)
        counts[i * NBLK + blockIdx.x] = h[i];
}

// ---------------- scan (3 kernels; scan_write_g runs IN-PLACE: out aliases in) ----------------

__global__ __launch_bounds__(256) void scan_sums(const int* __restrict__ in,
                                                 int* __restrict__ part) {
    int base = blockIdx.x * SCAN_TILE + threadIdx.x * SCAN_ITEMS;
    int s = 0;
#pragma unroll
    for (int k = 0; k < SCAN_ITEMS; ++k) {
        int idx = base + k;
        if (idx < SCAN_N) s += in[idx];
    }
    __shared__ int sm[256];
    sm[threadIdx.x] = s;
    __syncthreads();
    for (int off = 128; off > 0; off >>= 1) {
        if (threadIdx.x < off) sm[threadIdx.x] += sm[threadIdx.x + off];
        __syncthreads();
    }
    if (threadIdx.x == 0) part[blockIdx.x] = sm[0];
}

__global__ void scan_top_g(int* __restrict__ part) {
    if (threadIdx.x == 0 && blockIdx.x == 0) {
        int acc = 0;
        for (int i = 0; i < SCAN_NT; ++i) {
            int v = part[i];
            part[i] = acc;
            acc += v;
        }
    }
}

__global__ __launch_bounds__(256) void scan_write_g(const int* __restrict__ in,
                                                    const int* __restrict__ part,
                                                    int* __restrict__ out) {
    int t = threadIdx.x;
    int base = blockIdx.x * SCAN_TILE + t * SCAN_ITEMS;
    int local[SCAN_ITEMS];
    int s = 0;
#pragma unroll
    for (int k = 0; k < SCAN_ITEMS; ++k) {
        int idx = base + k;
        int v = (idx < SCAN_N) ? in[idx] : 0;
        local[k] = v;
        s += v;
    }
    __shared__ int sm[256];
    sm[t] = s;
    __syncthreads();
    for (int off = 1; off < 256; off <<= 1) {
        int v = (t >= off) ? sm[t - off] : 0;
        __syncthreads();
        sm[t] += v;
        __syncthreads();
    }
    int prefix = part[blockIdx.x] + sm[t] - s;  // exclusive
#pragma unroll
    for (int k = 0; k < SCAN_ITEMS; ++k) {
        int idx = base + k;
        if (idx < SCAN_N) {
            out[idx] = prefix;          // in-place safe: local[] already holds inputs
            prefix += local[k];
        }
    }
}

// ---------------- P2: LDS-sorted scatter -> coalesced slice bursts ----------------

__global__ __launch_bounds__(256) void p2_scatter(const int* __restrict__ ei,
                                                  const int* __restrict__ offs,
                                                  unsigned int* __restrict__ recs) {
    __shared__ int sorted[CHUNK];    // 50000 B
    __shared__ int lcur[NBUCK];      // sizes -> starts -> cursors -> inclusive ends
    __shared__ int gbase[NBUCK];     // global slice base per bucket
    __shared__ int sm[256];          // scan temp   (total ~63.5 KB < 64K)
    int t = threadIdx.x;
    int blk = blockIdx.x;

    // 1. load slice bases + local counts (offs column diffs)
    for (int b = t; b < NBUCK; b += 256) {
        int g = offs[b * NBLK + blk];
        gbase[b] = g;
        int nxt;
        if (blk + 1 < NBLK) nxt = offs[b * NBLK + blk + 1];
        else nxt = (b + 1 < NBUCK) ? offs[(b + 1) * NBLK] : NEDGES;
        lcur[b] = nxt - g;
    }
    __syncthreads();

    // 2. exclusive scan of local counts -> run starts (7 items/thread covers 1792 >= 1563)
    int base7 = t * 7;
    int loc[7];
    int s = 0;
#pragma unroll
    for (int k = 0; k < 7; ++k) {
        int idx = base7 + k;
        int v = (idx < NBUCK) ? lcur[idx] : 0;
        loc[k] = v;
        s += v;
    }
    sm[t] = s;
    __syncthreads();
    for (int off = 1; off < 256; off <<= 1) {
        int v = (t >= off) ? sm[t - off] : 0;
        __syncthreads();
        sm[t] += v;
        __syncthreads();
    }
    int run = sm[t] - s;
#pragma unroll
    for (int k = 0; k < 7; ++k) {
        int idx = base7 + k;
        if (idx < NBUCK) { lcur[idx] = run; run += loc[k]; }  // exclusive starts
    }
    __syncthreads();

    // 3. scatter chunk into LDS at local cursor positions
    int ebase = blk * CHUNK;
    for (int e = ebase + t; e < ebase + CHUNK; e += 256) {
        int src = ei[e];
        int d = ei[NEDGES + e];
        int b = d >> WB_SHIFT;
        int slot = atomicAdd(&lcur[b], 1);
        sorted[slot] = (int)((unsigned)src | ((unsigned)(d & (WB - 1)) << PSHIFT));
    }
    __syncthreads();
    // lcur[b] is now the INCLUSIVE end of run b (monotone non-decreasing)

    // 4. coalesced flush: find bucket by binary search, write run-relative
    for (int i = t; i < CHUNK; i += 256) {
        int lo = 0, hi = NBUCK - 1;
        while (lo < hi) {
            int mid = (lo + hi) >> 1;
            if (lcur[mid] > i) hi = mid; else lo = mid + 1;
        }
        int b = lo;
        int start = (b > 0) ? lcur[b - 1] : 0;
        recs[gbase[b] + (i - start)] = (unsigned)sorted[i];
    }
}

// ---------------- P2b: per-bucket sort-by-node (ONCE) + node_off + gx ----------------
// Replaces p3_dinv and gx_kernel, and removes the sort from l1/l2:
// sorts the bucket slice by local node in LDS, writes back src-only records
// (coalesced), emits absolute CSR offsets node_off[], and computes
// gx = rsqrt(1+deg)*x for its own 128 nodes from the in-LDS histogram.

__global__ __launch_bounds__(256) void p2b_sort(unsigned int* __restrict__ recs,
                                                const int* __restrict__ offs,
                                                const float* __restrict__ x,
                                                int* __restrict__ node_off,
                                                float4* __restrict__ gx) {
    __shared__ int sorted[SCAP];
    __shared__ int hist[WB], st[WB], cur[WB];
    int t = threadIdx.x;
    int b = blockIdx.x;
    if (t < WB) hist[t] = 0;
    __syncthreads();

    int beg = offs[b * NBLK];
    int end = (b + 1 < NBUCK) ? offs[(b + 1) * NBLK] : NEDGES;

    // pass A: local-node histogram
    for (int e = beg + t; e < end; e += 256)
        atomicAdd(&hist[recs[e] >> PSHIFT], 1);
    __syncthreads();

    // exclusive scan of hist[128]
    if (t < WB) cur[t] = hist[t];
    __syncthreads();
    for (int off = 1; off < WB; off <<= 1) {
        int v = 0;
        if (t < WB && t >= off) v = cur[t - off];
        __syncthreads();
        if (t < WB) cur[t] += v;
        __syncthreads();
    }
    if (t < WB) {
        st[t] = cur[t] - hist[t];
        cur[t] = st[t];
    }
    __syncthreads();

    // pass B: scatter src into LDS by node (recs L2-warm from pass A)
    for (int e = beg + t; e < end; e += 256) {
        unsigned r = recs[e];
        int slot = atomicAdd(&cur[r >> PSHIFT], 1);
        sorted[slot] = (int)(r & SRCMASK);
    }
    __syncthreads();

    // write back sorted src-only records (coalesced; all slice reads are done)
    int cnt = end - beg;
    for (int i = t; i < cnt; i += 256)
        recs[beg + i] = (unsigned)sorted[i];

    // per-node outputs: CSR offset + gx (dinv folded in, never materialized)
    int node = b * WB + t;
    if (t < WB && node < NNODES) {
        node_off[node] = beg + st[t];
        float di = rsqrtf((float)(1 + hist[t]));
        const float* xr = x + (size_t)node * FIN;
        float4 v0, v1;
        v0.x = xr[0] * di; v0.y = xr[1] * di; v0.z = xr[2] * di; v0.w = xr[3] * di;
        v1.x = xr[4] * di; v1.y = xr[5] * di; v1.z = xr[6] * di; v1.w = 0.0f;
        gx[(size_t)node * 2 + 0] = v0;
        gx[(size_t)node * 2 + 1] = v1;
    }
    if (b == 0 && t == 0) node_off[NNODES] = NEDGES;
}

// ---------------- L1: coalesced stage of pre-sorted slice -> register reduce -> MLP ----------------

__global__ __launch_bounds__(256) void l1_fast(const unsigned int* __restrict__ recs,
                                               const int* __restrict__ node_off,
                                               const float4* __restrict__ gx,
                                               const float* __restrict__ W1,
                                               const float* __restrict__ b1,
                                               const float* __restrict__ W2,
                                               float4* __restrict__ y) {
    __shared__ int sl_src[SCAP];
    __shared__ int noffs[WB + 1];
    __shared__ float acc[WB][9];
    __shared__ float sW1[FIN * FH1];
    __shared__ float sb1[FH1];
    __shared__ float sW2[FH1 * FH2];
    int t = threadIdx.x;
    for (int i = t; i < FIN * FH1; i += 256) sW1[i] = W1[i];
    if (t < FH1) sb1[t] = b1[t];
    for (int i = t; i < FH1 * FH2; i += 256) sW2[i] = W2[i];

    int b = blockIdx.x;
    for (int i = t; i <= WB; i += 256) {
        int idx = b * WB + i;
        noffs[i] = (idx >= NNODES) ? NEDGES : node_off[idx];
    }
    __syncthreads();

    int beg = noffs[0];
    int cnt_all = noffs[WB] - beg;
    for (int i = t; i < cnt_all; i += 256) sl_src[i] = (int)recs[beg + i];
    __syncthreads();

    // segmented reduce: 2 lanes per node, registers, NO atomics
    int n = t >> 1;
    int hq = t & 1;
    int base = noffs[n] - beg;
    int cnt = noffs[n + 1] - noffs[n];
    float ax = 0.0f, ay = 0.0f, az = 0.0f, aw = 0.0f;
    int k = 0;
    for (; k + 3 < cnt; k += 4) {
        int s0 = sl_src[base + k];
        int s1 = sl_src[base + k + 1];
        int s2 = sl_src[base + k + 2];
        int s3 = sl_src[base + k + 3];
        float4 v0 = gx[(size_t)s0 * 2 + hq];
        float4 v1 = gx[(size_t)s1 * 2 + hq];
        float4 v2 = gx[(size_t)s2 * 2 + hq];
        float4 v3 = gx[(size_t)s3 * 2 + hq];
        ax += v0.x + v1.x; ay += v0.y + v1.y;
        az += v0.z + v1.z; aw += v0.w + v1.w;
        ax += v2.x + v3.x; ay += v2.y + v3.y;
        az += v2.z + v3.z; aw += v2.w + v3.w;
    }
    for (; k < cnt; ++k) {
        int s0 = sl_src[base + k];
        float4 v0 = gx[(size_t)s0 * 2 + hq];
        ax += v0.x; ay += v0.y; az += v0.z; aw += v0.w;
    }
    int kb = hq * 4;
    acc[n][kb + 0] = ax; acc[n][kb + 1] = ay;
    acc[n][kb + 2] = az; acc[n][kb + 3] = aw;
    __syncthreads();

    int node = b * WB + t;
    if (t >= WB || node >= NNODES) return;

    float di = rsqrtf((float)(1 + (noffs[t + 1] - noffs[t])));  // == p3's dinv
    float4 g0 = gx[(size_t)node * 2], g1 = gx[(size_t)node * 2 + 1];
    float xa[FIN];
    xa[0] = (acc[t][0] + g0.x) * di;
    xa[1] = (acc[t][1] + g0.y) * di;
    xa[2] = (acc[t][2] + g0.z) * di;
    xa[3] = (acc[t][3] + g0.w) * di;
    xa[4] = (acc[t][4] + g1.x) * di;
    xa[5] = (acc[t][5] + g1.y) * di;
    xa[6] = (acc[t][6] + g1.z) * di;

    float h1[FH1];
#pragma unroll
    for (int j = 0; j < FH1; ++j) h1[j] = sb1[j];
#pragma unroll
    for (int f = 0; f < FIN; ++f) {
        float xv = xa[f];
#pragma unroll
        for (int j = 0; j < FH1; ++j) h1[j] = fmaf(xv, sW1[f * FH1 + j], h1[j]);
    }
#pragma unroll
    for (int j = 0; j < FH1; ++j) h1[j] = fmaxf(h1[j], 0.0f);

    float yv[FH2];
#pragma unroll
    for (int j = 0; j < FH2; ++j) yv[j] = 0.0f;
#pragma unroll
    for (int k2 = 0; k2 < FH1; ++k2) {
        float hv = h1[k2];
#pragma unroll
        for (int j = 0; j < FH2; ++j) yv[j] = fmaf(hv, sW2[k2 * FH2 + j], yv[j]);
    }

    size_t yb = (size_t)node * 4;
    float4 o;
    o.x = yv[0] * di; o.y = yv[1] * di; o.z = yv[2] * di; o.w = yv[3] * di;
    y[yb + 0] = o;
    o.x = yv[4] * di; o.y = yv[5] * di; o.z = yv[6] * di; o.w = yv[7] * di;
    y[yb + 1] = o;
    o.x = yv[8] * di; o.y = yv[9] * di; o.z = yv[10] * di; o.w = yv[11] * di;
    y[yb + 2] = o;
    o.x = yv[12] * di; o.y = yv[13] * di; o.z = yv[14] * di; o.w = yv[15] * di;
    y[yb + 3] = o;
}

// ---------------- L2: coalesced stage of pre-sorted slice -> register reduce -> MLP ----------------

__global__ __launch_bounds__(256) void l2_fast(const unsigned int* __restrict__ recs,
                                               const int* __restrict__ node_off,
                                               const float4* __restrict__ y,
                                               const float* __restrict__ b2,
                                               const float* __restrict__ Wfc,
                                               const float* __restrict__ bfc,
                                               float2* __restrict__ out) {
    __shared__ int sl_src[SCAP];
    __shared__ int noffs[WB + 1];
    __shared__ float acc[WB][17];
    __shared__ float sb2[FH2];
    __shared__ float sWfc[FH2 * NC];
    __shared__ float sbfc[NC];
    int t = threadIdx.x;
    if (t < FH2) sb2[t] = b2[t];
    if (t < FH2 * NC) sWfc[t] = Wfc[t];
    if (t < NC) sbfc[t] = bfc[t];

    int b = blockIdx.x;
    for (int i = t; i <= WB; i += 256) {
        int idx = b * WB + i;
        noffs[i] = (idx >= NNODES) ? NEDGES : node_off[idx];
    }
    __syncthreads();

    int beg = noffs[0];
    int cnt_all = noffs[WB] - beg;
    for (int i = t; i < cnt_all; i += 256) sl_src[i] = (int)recs[beg + i];
    __syncthreads();

    // segmented reduce: 4 lanes per node, 2 rounds of 64 nodes, registers, NO atomics
    int q = t & 3;
#pragma unroll
    for (int r = 0; r < 2; ++r) {
        int n = (t >> 2) + 64 * r;
        int base = noffs[n] - beg;
        int cnt = noffs[n + 1] - noffs[n];
        float ax = 0.0f, ay = 0.0f, az = 0.0f, aw = 0.0f;
        int k = 0;
        for (; k + 3 < cnt; k += 4) {
            int s0 = sl_src[base + k];
            int s1 = sl_src[base + k + 1];
            int s2 = sl_src[base + k + 2];
            int s3 = sl_src[base + k + 3];
            float4 v0 = y[(size_t)s0 * 4 + q];
            float4 v1 = y[(size_t)s1 * 4 + q];
            float4 v2 = y[(size_t)s2 * 4 + q];
            float4 v3 = y[(size_t)s3 * 4 + q];
            ax += v0.x + v1.x; ay += v0.y + v1.y;
            az += v0.z + v1.z; aw += v0.w + v1.w;
            ax += v2.x + v3.x; ay += v2.y + v3.y;
            az += v2.z + v3.z; aw += v2.w + v3.w;
        }
        for (; k < cnt; ++k) {
            int s0 = sl_src[base + k];
            float4 v0 = y[(size_t)s0 * 4 + q];
            ax += v0.x; ay += v0.y; az += v0.z; aw += v0.w;
        }
        int kb = q * 4;
        acc[n][kb + 0] = ax; acc[n][kb + 1] = ay;
        acc[n][kb + 2] = az; acc[n][kb + 3] = aw;
    }
    __syncthreads();

    int node = b * WB + t;
    if (t >= WB || node >= NNODES) return;

    float di = rsqrtf((float)(1 + (noffs[t + 1] - noffs[t])));
    size_t yb = (size_t)node * 4;
    float4 s0 = y[yb + 0], s1 = y[yb + 1], s2 = y[yb + 2], s3 = y[yb + 3];
    float self[FH2] = {s0.x, s0.y, s0.z, s0.w, s1.x, s1.y, s1.z, s1.w,
                       s2.x, s2.y, s2.z, s2.w, s3.x, s3.y, s3.z, s3.w};

    float o0 = sbfc[0], o1 = sbfc[1];
#pragma unroll
    for (int k = 0; k < FH2; ++k) {
        float h = fmaxf(fmaf(di, acc[t][k] + self[k], sb2[k]), 0.0f);
        o0 = fmaf(h, sWfc[k * NC + 0], o0);
        o1 = fmaf(h, sWfc[k * NC + 1], o1);
    }
    float2 ov; ov.x = o0; ov.y = o1;
    out[node] = ov;
}

// ---------------- launch ----------------

extern "C" void kernel_launch(void* const* d_in, const int* in_sizes, int n_in,
                              void* d_out, int out_size, void* d_ws, size_t ws_size,
                              hipStream_t stream) {
    const float* x   = (const float*)d_in[0];
    const int*   ei  = (const int*)d_in[1];
    const float* W1  = (const float*)d_in[2];
    const float* b1  = (const float*)d_in[3];
    const float* W2  = (const float*)d_in[4];
    const float* b2  = (const float*)d_in[5];
    const float* Wfc = (const float*)d_in[6];
    const float* bfc = (const float*)d_in[7];
    float* out = (float*)d_out;

    char* p = (char*)d_ws;
    auto carve = [&](size_t bytes) -> char* {
        char* r = p;
        p += (bytes + 255) & ~(size_t)255;
        return r;
    };
    int*      counts   = (int*)carve((size_t)SCAN_N * 4);       // scanned IN-PLACE -> offs
    int*      part     = (int*)carve(256 * 4);
    int*      node_off = (int*)carve((size_t)(NNODES + 1) * 4); // replaces old dinv slot
    float*    gx       = (float*)carve((size_t)NNODES * 8 * 4);
    float*    y        = (float*)carve((size_t)NNODES * 16 * 4);
    unsigned* recs     = (unsigned*)carve((size_t)NEDGES * 4);
    // total ~48.8 MB (within the proven round-7 footprint; dinv array eliminated)
    int* offs = counts;  // alias: scan_write_g rewrites counts into exclusive offsets

    p1_count<<<NBLK, 256, 0, stream>>>(ei, counts);
    scan_sums<<<SCAN_NT, 256, 0, stream>>>(counts, part);
    scan_top_g<<<1, 64, 0, stream>>>(part);
    scan_write_g<<<SCAN_NT, 256, 0, stream>>>(counts, part, offs);  // in-place
    p2_scatter<<<NBLK, 256, 0, stream>>>(ei, offs, recs);
    p2b_sort<<<NBUCK, 256, 0, stream>>>(recs, offs, x, node_off, (float4*)gx);
    l1_fast<<<NBUCK, 256, 0, stream>>>(recs, node_off, (const float4*)gx,
                                       W1, b1, W2, (float4*)y);
    l2_fast<<<NBUCK, 256, 0, stream>>>(recs, node_off, (const float4*)y,
                                       b2, Wfc, bfc, (float2*)out);
}

// Round 9
// 347.341 us; speedup vs baseline: 4.1920x; 1.0807x over previous
//
#include <hip/hip_runtime.h>

#define NNODES 200000
#define NEDGES 6400000
#define FIN 7
#define FH1 32
#define FH2 16
#define NC 2

// bucketing
#define WB 128                       // nodes per bucket
#define WB_SHIFT 7
#define NBUCK ((NNODES + WB - 1) / WB)   // 1563
#define NBLK 512                      // blocks for the sort/scatter pass (2/CU)
#define CHUNK (NEDGES / NBLK)         // 12500 exact (512*12500 = 6.4M)
#define PSHIFT 18
#define SRCMASK ((1u << PSHIFT) - 1)

// padded per-bucket region in recs: mean 4096, sd 64 -> 8-sigma margin
#define RSTRIDE 4608
// per-bucket LDS staging capacity (proven since round 5)
#define SCAP 5120

// ---------------- zero bucket cursors ----------------

__global__ __launch_bounds__(256) void zero_cnt(int* __restrict__ cnt) {
    int i = blockIdx.x * 256 + threadIdx.x;
    if (i < NBUCK) cnt[i] = 0;
}

// ---------------- P2: LDS chunk-sort + global run reservation + coalesced flush ----------------
// Replaces p1_count + 3 scan kernels + old p2: each block histograms its own
// 12500-edge chunk, sorts it by bucket in LDS, reserves each bucket-run's
// global slot with ONE atomicAdd, and flushes runs coalesced into the
// bucket's padded region. Within-bucket run order is nondeterministic --
// irrelevant, since p2b re-sorts every bucket by node.

__global__ __launch_bounds__(256) void p2_sortres(const int* __restrict__ ei,
                                                  int* __restrict__ bucket_cur,
                                                  unsigned int* __restrict__ recs) {
    __shared__ int sorted[CHUNK];    // 50000 B
    __shared__ int lcur[NBUCK];      // counts -> starts -> cursors -> inclusive ends
    __shared__ int gbase[NBUCK];     // reserved global base per bucket run
    __shared__ int sm[256];          // scan temp (total ~63.5 KB)
    int t = threadIdx.x;
    int blk = blockIdx.x;

    for (int i = t; i < NBUCK; i += 256) lcur[i] = 0;
    __syncthreads();

    // 1. histogram this chunk by bucket
    int ebase = blk * CHUNK;
    for (int e = ebase + t; e < ebase + CHUNK; e += 256)
        atomicAdd(&lcur[ei[NEDGES + e] >> WB_SHIFT], 1);
    __syncthreads();

    // 2. exclusive scan of lcur (7 items/thread covers 1792 >= 1563)
    int base7 = t * 7;
    int loc[7];
    int s = 0;
#pragma unroll
    for (int k = 0; k < 7; ++k) {
        int idx = base7 + k;
        int v = (idx < NBUCK) ? lcur[idx] : 0;
        loc[k] = v;
        s += v;
    }
    sm[t] = s;
    __syncthreads();
    for (int off = 1; off < 256; off <<= 1) {
        int v = (t >= off) ? sm[t - off] : 0;
        __syncthreads();
        sm[t] += v;
        __syncthreads();
    }
    int run = sm[t] - s;
#pragma unroll
    for (int k = 0; k < 7; ++k) {
        int idx = base7 + k;
        if (idx < NBUCK) { lcur[idx] = run; run += loc[k]; }  // exclusive starts
    }
    __syncthreads();

    // 3. scatter chunk into LDS at cursor positions
    for (int e = ebase + t; e < ebase + CHUNK; e += 256) {
        int src = ei[e];
        int d = ei[NEDGES + e];
        int b = d >> WB_SHIFT;
        int slot = atomicAdd(&lcur[b], 1);
        sorted[slot] = (int)((unsigned)src | ((unsigned)(d & (WB - 1)) << PSHIFT));
    }
    __syncthreads();
    // lcur[b] is now the INCLUSIVE end of run b

    // 4. reserve global slots: one atomic per non-empty bucket run
    for (int b = t; b < NBUCK; b += 256) {
        int st_ = (b > 0) ? lcur[b - 1] : 0;
        int len = lcur[b] - st_;
        if (len > 0)
            gbase[b] = b * RSTRIDE + atomicAdd(&bucket_cur[b], len);
    }
    __syncthreads();

    // 5. coalesced flush: find bucket by binary search, write run-relative
    for (int i = t; i < CHUNK; i += 256) {
        int lo = 0, hi = NBUCK - 1;
        while (lo < hi) {
            int mid = (lo + hi) >> 1;
            if (lcur[mid] > i) hi = mid; else lo = mid + 1;
        }
        int b = lo;
        int start = (b > 0) ? lcur[b - 1] : 0;
        recs[(size_t)gbase[b] + (i - start)] = (unsigned)sorted[i];
    }
}

// ---------------- P2b: per-bucket sort-by-node + node_off + gx ----------------

__global__ __launch_bounds__(256) void p2b_sort(unsigned int* __restrict__ recs,
                                                const int* __restrict__ bucket_cur,
                                                const float* __restrict__ x,
                                                int* __restrict__ node_off,
                                                float4* __restrict__ gx) {
    __shared__ int sorted[SCAP];
    __shared__ int hist[WB], st[WB], cur[WB];
    int t = threadIdx.x;
    int b = blockIdx.x;
    if (t < WB) hist[t] = 0;
    __syncthreads();

    int beg = b * RSTRIDE;
    int cnt = bucket_cur[b];

    // pass A: local-node histogram
    for (int i = t; i < cnt; i += 256)
        atomicAdd(&hist[recs[(size_t)beg + i] >> PSHIFT], 1);
    __syncthreads();

    // exclusive scan of hist[128]
    if (t < WB) cur[t] = hist[t];
    __syncthreads();
    for (int off = 1; off < WB; off <<= 1) {
        int v = 0;
        if (t < WB && t >= off) v = cur[t - off];
        __syncthreads();
        if (t < WB) cur[t] += v;
        __syncthreads();
    }
    if (t < WB) {
        st[t] = cur[t] - hist[t];
        cur[t] = st[t];
    }
    __syncthreads();

    // pass B: scatter src into LDS by node
    for (int i = t; i < cnt; i += 256) {
        unsigned r = recs[(size_t)beg + i];
        int slot = atomicAdd(&cur[r >> PSHIFT], 1);
        sorted[slot] = (int)(r & SRCMASK);
    }
    __syncthreads();

    // write back sorted src-only records (coalesced)
    for (int i = t; i < cnt; i += 256)
        recs[(size_t)beg + i] = (unsigned)sorted[i];

    // per-node outputs: absolute CSR offset + gx (dinv folded in)
    int node = b * WB + t;
    if (t < WB && node < NNODES) {
        node_off[node] = beg + st[t];
        float di = rsqrtf((float)(1 + hist[t]));
        const float* xr = x + (size_t)node * FIN;
        float4 v0, v1;
        v0.x = xr[0] * di; v0.y = xr[1] * di; v0.z = xr[2] * di; v0.w = xr[3] * di;
        v1.x = xr[4] * di; v1.y = xr[5] * di; v1.z = xr[6] * di; v1.w = 0.0f;
        gx[(size_t)node * 2 + 0] = v0;
        gx[(size_t)node * 2 + 1] = v1;
    }
}

// ---------------- L1: coalesced stage of pre-sorted slice -> register reduce -> MLP ----------------

__global__ __launch_bounds__(256) void l1_fast(const unsigned int* __restrict__ recs,
                                               const int* __restrict__ node_off,
                                               const int* __restrict__ bucket_cur,
                                               const float4* __restrict__ gx,
                                               const float* __restrict__ W1,
                                               const float* __restrict__ b1,
                                               const float* __restrict__ W2,
                                               float4* __restrict__ y) {
    __shared__ int sl_src[SCAP];
    __shared__ int noffs[WB + 1];
    __shared__ float acc[WB][9];
    __shared__ float sW1[FIN * FH1];
    __shared__ float sb1[FH1];
    __shared__ float sW2[FH1 * FH2];
    int t = threadIdx.x;
    for (int i = t; i < FIN * FH1; i += 256) sW1[i] = W1[i];
    if (t < FH1) sb1[t] = b1[t];
    for (int i = t; i < FH1 * FH2; i += 256) sW2[i] = W2[i];

    int b = blockIdx.x;
    int beg = b * RSTRIDE;
    int cnt_all = bucket_cur[b];
    for (int i = t; i < WB; i += 256) {
        int idx = b * WB + i;
        noffs[i] = (idx < NNODES) ? node_off[idx] : beg + cnt_all;
    }
    if (t == 0) noffs[WB] = beg + cnt_all;
    __syncthreads();

    for (int i = t; i < cnt_all; i += 256) sl_src[i] = (int)recs[(size_t)beg + i];
    __syncthreads();

    // segmented reduce: 2 lanes per node, registers, NO atomics
    int n = t >> 1;
    int hq = t & 1;
    int base = noffs[n] - beg;
    int cnt = noffs[n + 1] - noffs[n];
    float ax = 0.0f, ay = 0.0f, az = 0.0f, aw = 0.0f;
    int k = 0;
    for (; k + 3 < cnt; k += 4) {
        int s0 = sl_src[base + k];
        int s1 = sl_src[base + k + 1];
        int s2 = sl_src[base + k + 2];
        int s3 = sl_src[base + k + 3];
        float4 v0 = gx[(size_t)s0 * 2 + hq];
        float4 v1 = gx[(size_t)s1 * 2 + hq];
        float4 v2 = gx[(size_t)s2 * 2 + hq];
        float4 v3 = gx[(size_t)s3 * 2 + hq];
        ax += v0.x + v1.x; ay += v0.y + v1.y;
        az += v0.z + v1.z; aw += v0.w + v1.w;
        ax += v2.x + v3.x; ay += v2.y + v3.y;
        az += v2.z + v3.z; aw += v2.w + v3.w;
    }
    for (; k < cnt; ++k) {
        int s0 = sl_src[base + k];
        float4 v0 = gx[(size_t)s0 * 2 + hq];
        ax += v0.x; ay += v0.y; az += v0.z; aw += v0.w;
    }
    int kb = hq * 4;
    acc[n][kb + 0] = ax; acc[n][kb + 1] = ay;
    acc[n][kb + 2] = az; acc[n][kb + 3] = aw;
    __syncthreads();

    int node = b * WB + t;
    if (t >= WB || node >= NNODES) return;

    float di = rsqrtf((float)(1 + (noffs[t + 1] - noffs[t])));
    float4 g0 = gx[(size_t)node * 2], g1 = gx[(size_t)node * 2 + 1];
    float xa[FIN];
    xa[0] = (acc[t][0] + g0.x) * di;
    xa[1] = (acc[t][1] + g0.y) * di;
    xa[2] = (acc[t][2] + g0.z) * di;
    xa[3] = (acc[t][3] + g0.w) * di;
    xa[4] = (acc[t][4] + g1.x) * di;
    xa[5] = (acc[t][5] + g1.y) * di;
    xa[6] = (acc[t][6] + g1.z) * di;

    float h1[FH1];
#pragma unroll
    for (int j = 0; j < FH1; ++j) h1[j] = sb1[j];
#pragma unroll
    for (int f = 0; f < FIN; ++f) {
        float xv = xa[f];
#pragma unroll
        for (int j = 0; j < FH1; ++j) h1[j] = fmaf(xv, sW1[f * FH1 + j], h1[j]);
    }
#pragma unroll
    for (int j = 0; j < FH1; ++j) h1[j] = fmaxf(h1[j], 0.0f);

    float yv[FH2];
#pragma unroll
    for (int j = 0; j < FH2; ++j) yv[j] = 0.0f;
#pragma unroll
    for (int k2 = 0; k2 < FH1; ++k2) {
        float hv = h1[k2];
#pragma unroll
        for (int j = 0; j < FH2; ++j) yv[j] = fmaf(hv, sW2[k2 * FH2 + j], yv[j]);
    }

    size_t yb = (size_t)node * 4;
    float4 o;
    o.x = yv[0] * di; o.y = yv[1] * di; o.z = yv[2] * di; o.w = yv[3] * di;
    y[yb + 0] = o;
    o.x = yv[4] * di; o.y = yv[5] * di; o.z = yv[6] * di; o.w = yv[7] * di;
    y[yb + 1] = o;
    o.x = yv[8] * di; o.y = yv[9] * di; o.z = yv[10] * di; o.w = yv[11] * di;
    y[yb + 2] = o;
    o.x = yv[12] * di; o.y = yv[13] * di; o.z = yv[14] * di; o.w = yv[15] * di;
    y[yb + 3] = o;
}

// ---------------- L2: coalesced stage of pre-sorted slice -> register reduce -> MLP ----------------

__global__ __launch_bounds__(256) void l2_fast(const unsigned int* __restrict__ recs,
                                               const int* __restrict__ node_off,
                                               const int* __restrict__ bucket_cur,
                                               const float4* __restrict__ y,
                                               const float* __restrict__ b2,
                                               const float* __restrict__ Wfc,
                                               const float* __restrict__ bfc,
                                               float2* __restrict__ out) {
    __shared__ int sl_src[SCAP];
    __shared__ int noffs[WB + 1];
    __shared__ float acc[WB][17];
    __shared__ float sb2[FH2];
    __shared__ float sWfc[FH2 * NC];
    __shared__ float sbfc[NC];
    int t = threadIdx.x;
    if (t < FH2) sb2[t] = b2[t];
    if (t < FH2 * NC) sWfc[t] = Wfc[t];
    if (t < NC) sbfc[t] = bfc[t];

    int b = blockIdx.x;
    int beg = b * RSTRIDE;
    int cnt_all = bucket_cur[b];
    for (int i = t; i < WB; i += 256) {
        int idx = b * WB + i;
        noffs[i] = (idx < NNODES) ? node_off[idx] : beg + cnt_all;
    }
    if (t == 0) noffs[WB] = beg + cnt_all;
    __syncthreads();

    for (int i = t; i < cnt_all; i += 256) sl_src[i] = (int)recs[(size_t)beg + i];
    __syncthreads();

    // segmented reduce: 4 lanes per node, 2 rounds of 64 nodes, registers, NO atomics
    int q = t & 3;
#pragma unroll
    for (int r = 0; r < 2; ++r) {
        int n = (t >> 2) + 64 * r;
        int base = noffs[n] - beg;
        int cnt = noffs[n + 1] - noffs[n];
        float ax = 0.0f, ay = 0.0f, az = 0.0f, aw = 0.0f;
        int k = 0;
        for (; k + 3 < cnt; k += 4) {
            int s0 = sl_src[base + k];
            int s1 = sl_src[base + k + 1];
            int s2 = sl_src[base + k + 2];
            int s3 = sl_src[base + k + 3];
            float4 v0 = y[(size_t)s0 * 4 + q];
            float4 v1 = y[(size_t)s1 * 4 + q];
            float4 v2 = y[(size_t)s2 * 4 + q];
            float4 v3 = y[(size_t)s3 * 4 + q];
            ax += v0.x + v1.x; ay += v0.y + v1.y;
            az += v0.z + v1.z; aw += v0.w + v1.w;
            ax += v2.x + v3.x; ay += v2.y + v3.y;
            az += v2.z + v3.z; aw += v2.w + v3.w;
        }
        for (; k < cnt; ++k) {
            int s0 = sl_src[base + k];
            float4 v0 = y[(size_t)s0 * 4 + q];
            ax += v0.x; ay += v0.y; az += v0.z; aw += v0.w;
        }
        int kb = q * 4;
        acc[n][kb + 0] = ax; acc[n][kb + 1] = ay;
        acc[n][kb + 2] = az; acc[n][kb + 3] = aw;
    }
    __syncthreads();

    int node = b * WB + t;
    if (t >= WB || node >= NNODES) return;

    float di = rsqrtf((float)(1 + (noffs[t + 1] - noffs[t])));
    size_t yb = (size_t)node * 4;
    float4 s0 = y[yb + 0], s1 = y[yb + 1], s2 = y[yb + 2], s3 = y[yb + 3];
    float self[FH2] = {s0.x, s0.y, s0.z, s0.w, s1.x, s1.y, s1.z, s1.w,
                       s2.x, s2.y, s2.z, s2.w, s3.x, s3.y, s3.z, s3.w};

    float o0 = sbfc[0], o1 = sbfc[1];
#pragma unroll
    for (int k = 0; k < FH2; ++k) {
        float h = fmaxf(fmaf(di, acc[t][k] + self[k], sb2[k]), 0.0f);
        o0 = fmaf(h, sWfc[k * NC + 0], o0);
        o1 = fmaf(h, sWfc[k * NC + 1], o1);
    }
    float2 ov; ov.x = o0; ov.y = o1;
    out[node] = ov;
}

// ---------------- launch ----------------

extern "C" void kernel_launch(void* const* d_in, const int* in_sizes, int n_in,
                              void* d_out, int out_size, void* d_ws, size_t ws_size,
                              hipStream_t stream) {
    const float* x   = (const float*)d_in[0];
    const int*   ei  = (const int*)d_in[1];
    const float* W1  = (const float*)d_in[2];
    const float* b1  = (const float*)d_in[3];
    const float* W2  = (const float*)d_in[4];
    const float* b2  = (const float*)d_in[5];
    const float* Wfc = (const float*)d_in[6];
    const float* bfc = (const float*)d_in[7];
    float* out = (float*)d_out;

    char* p = (char*)d_ws;
    auto carve = [&](size_t bytes) -> char* {
        char* r = p;
        p += (bytes + 255) & ~(size_t)255;
        return r;
    };
    int*      bucket_cur = (int*)carve((size_t)NBUCK * 4);
    int*      node_off   = (int*)carve((size_t)NNODES * 4);
    float*    gx         = (float*)carve((size_t)NNODES * 8 * 4);
    float*    y          = (float*)carve((size_t)NNODES * 16 * 4);
    unsigned* recs       = (unsigned*)carve((size_t)NBUCK * RSTRIDE * 4);
    // total ~48.8 MB (padded recs 28.8 MB; counts matrix + scans eliminated)

    zero_cnt<<<(NBUCK + 255) / 256, 256, 0, stream>>>(bucket_cur);
    p2_sortres<<<NBLK, 256, 0, stream>>>(ei, bucket_cur, recs);
    p2b_sort<<<NBUCK, 256, 0, stream>>>(recs, bucket_cur, x, node_off, (float4*)gx);
    l1_fast<<<NBUCK, 256, 0, stream>>>(recs, node_off, bucket_cur, (const float4*)gx,
                                       W1, b1, W2, (float4*)y);
    l2_fast<<<NBUCK, 256, 0, stream>>>(recs, node_off, bucket_cur, (const float4*)y,
                                       b2, Wfc, bfc, (float2*)out);
}